// Round 2
// baseline (585.499 us; speedup 1.0000x reference)
//
#include <hip/hip_runtime.h>

// ---------- bf16 helpers (raw ushort representation) ----------
__device__ __forceinline__ float bf2f(ushort u) {
    union { uint i; float f; } c; c.i = ((uint)u) << 16; return c.f;
}
__device__ __forceinline__ ushort f2bf(float f) {
    union { float f; uint i; } c; c.f = f;
    uint b = c.i;
    uint r = (b + 0x7fffu + ((b >> 16) & 1u)) >> 16;
    return (ushort)r;
}

typedef __bf16 v8bf __attribute__((ext_vector_type(8)));
typedef float  v4f  __attribute__((ext_vector_type(4)));

// ---------- dtype sniff: are float inputs f32 (flag=1) or bf16 (flag=0)? ----------
// If data is f32, the LOW u16 of each word is f32 mantissa bits -> decoded as
// bf16 it has a uniform exponent (44% of values have |v| >= 2^16). If data is
// bf16, every u16 is a sane value (|x| ~ N(0,1) -> exponent < 143 always).
__global__ __launch_bounds__(256) void sniff_kernel(const uint* __restrict__ words, int* __restrict__ flag) {
    __shared__ int s[256];
    int t = threadIdx.x;
    int bad = 0;
    for (int i = t; i < 2048; i += 256) {
        uint w = words[i];
        uint exp = (w >> 7) & 0xffu;   // exponent of low u16 as bf16
        if (exp >= 143u) bad++;        // |val| >= 2^16 -> impossible for sane data
    }
    s[t] = bad;
    __syncthreads();
    for (int o = 128; o; o >>= 1) {
        if (t < o) s[t] += s[t + o];
        __syncthreads();
    }
    if (t == 0) *flag = (s[0] > 64) ? 1 : 0;
}

__device__ __forceinline__ ushort load_conv(const void* src, int i, int isf32) {
    return isf32 ? f2bf(((const float*)src)[i]) : ((const ushort*)src)[i];
}

// ---------- convert x to canonical bf16 ----------
__global__ __launch_bounds__(256) void convert_x(const void* __restrict__ src, ushort* __restrict__ dst,
                                                 int n, const int* __restrict__ flag) {
    int i = blockIdx.x * 256 + threadIdx.x;
    if (i >= n) return;
    dst[i] = load_conv(src, i, *flag);
}

// ---------- small params: 4 biases + mp_w1 + mp_b1 + mp_w2 + mp_b2 ----------
struct SmallSrcs { const void* p[8]; };
// offsets: lin_b0 0, agg_b0 128, lin_b1 256, agg_b1 384, mp_w1 512, mp_b1 16896, mp_w2 17024, mp_b2 17280 (end 17282)
__global__ __launch_bounds__(256) void convert_small(SmallSrcs s, ushort* __restrict__ dst,
                                                     const int* __restrict__ flag) {
    const int offs[9] = {0, 128, 256, 384, 512, 16896, 17024, 17280, 17282};
    int idx = blockIdx.x * 256 + threadIdx.x;
    if (idx >= 17282) return;
    int seg = 0;
    while (idx >= offs[seg + 1]) seg++;
    dst[idx] = load_conv(s.p[seg], idx - offs[seg], *flag);
}

// ---------- transpose the 4 weight matrices (W[K][128] -> Wt[128][K]), flag-aware ----------
__global__ __launch_bounds__(256) void transpose_all(
    const void* __restrict__ w0, const void* __restrict__ wa0,
    const void* __restrict__ w1, const void* __restrict__ wa1,
    ushort* __restrict__ t0, ushort* __restrict__ ta0,
    ushort* __restrict__ t1, ushort* __restrict__ ta1,
    const int* __restrict__ flag) {
    int idx = blockIdx.x * 256 + threadIdx.x;   // 0 .. 98303
    const void* W; ushort* T; int K; int local;
    if (idx < 16384)      { W = w0;  T = t0;  K = 128; local = idx; }
    else if (idx < 49152) { W = wa0; T = ta0; K = 256; local = idx - 16384; }
    else if (idx < 65536) { W = w1;  T = t1;  K = 128; local = idx - 49152; }
    else                  { W = wa1; T = ta1; K = 256; local = idx - 65536; }
    ushort v = load_conv(W, local, *flag);
    int k = local >> 7;       // row in W
    int n = local & 127;      // col in W
    T[(size_t)n * K + k] = v;
}

// ---------- CSR build ----------
__global__ __launch_bounds__(256) void count_deg(const int* __restrict__ dst, int* __restrict__ deg, int E) {
    int i = blockIdx.x * 256 + threadIdx.x;
    if (i < E) atomicAdd(&deg[dst[i]], 1);
}

__global__ __launch_bounds__(256) void scan_kernel(const int* __restrict__ deg, int* __restrict__ rowptr,
                                                   int* __restrict__ cursor, int n) {
    __shared__ int sums[256];
    int t = threadIdx.x;
    int CH = (n + 255) / 256;
    int lo = t * CH, hi = min(lo + CH, n);
    int s = 0;
    for (int i = lo; i < hi; i++) s += deg[i];
    sums[t] = s;
    __syncthreads();
    for (int off = 1; off < 256; off <<= 1) {
        int v = (t >= off) ? sums[t - off] : 0;
        __syncthreads();
        sums[t] += v;
        __syncthreads();
    }
    int run = sums[t] - s;  // exclusive
    for (int i = lo; i < hi; i++) {
        rowptr[i] = run; cursor[i] = run;
        run += deg[i];
    }
    if (t == 255) rowptr[n] = sums[255];
}

__global__ __launch_bounds__(256) void fill_kernel(const int* __restrict__ src, const int* __restrict__ dst,
                                                   int* __restrict__ cursor, int* __restrict__ csr_src, int E) {
    int i = blockIdx.x * 256 + threadIdx.x;
    if (i < E) {
        int pos = atomicAdd(&cursor[dst[i]], 1);
        csr_src[pos] = src[i];
    }
}

// ---------- MFMA GEMM: C[M][128] = relu(A @ Bt^T + bias), optional row-L2-normalize ----------
// Bt is pre-transposed weights: Bt[n][k]; stage 0 reads A0 (k<128), stage 1 A1 (k>=128)
template <int NSTAGE, bool NORM>
__global__ __launch_bounds__(256) void gemm_kernel(
    const ushort* __restrict__ A0, const ushort* __restrict__ A1,
    const ushort* __restrict__ Bt, const ushort* __restrict__ bias,
    ushort* __restrict__ Cout, int M) {
    __shared__ __bf16 As[128 * 72];  // 64 k-chunk, stride 72 (pad 8)
    __shared__ __bf16 Bs[128 * 72];
    const int t = threadIdx.x;
    const int w = t >> 6, lane = t & 63, ln = lane & 15, q = lane >> 4;
    const int blockRow = blockIdx.x * 128;
    const int K = NSTAGE * 128;

    v4f acc[2][8];
#pragma unroll
    for (int i = 0; i < 2; i++)
#pragma unroll
        for (int j = 0; j < 8; j++) acc[i][j] = (v4f){0.f, 0.f, 0.f, 0.f};

    for (int kc = 0; kc < K; kc += 64) {
        const ushort* Ap = (kc < 128) ? A0 : A1;
        int kin = kc & 127;
#pragma unroll
        for (int i = 0; i < 4; i++) {
            int c = i * 256 + t;
            int row = c >> 3, c8 = c & 7;
            int grow = blockRow + row; if (grow >= M) grow = M - 1;
            *(uint4*)&As[row * 72 + c8 * 8] = *(const uint4*)(Ap + (size_t)grow * 128 + kin + c8 * 8);
            *(uint4*)&Bs[row * 72 + c8 * 8] = *(const uint4*)(Bt + (size_t)row * K + kc + c8 * 8);
        }
        __syncthreads();
#pragma unroll
        for (int k0 = 0; k0 < 64; k0 += 32) {
            v8bf a0 = *(const v8bf*)&As[(w * 32 + ln) * 72 + k0 + q * 8];
            v8bf a1 = *(const v8bf*)&As[(w * 32 + 16 + ln) * 72 + k0 + q * 8];
#pragma unroll
            for (int nt = 0; nt < 8; nt++) {
                v8bf b = *(const v8bf*)&Bs[(nt * 16 + ln) * 72 + k0 + q * 8];
                acc[0][nt] = __builtin_amdgcn_mfma_f32_16x16x32_bf16(a0, b, acc[0][nt], 0, 0, 0);
                acc[1][nt] = __builtin_amdgcn_mfma_f32_16x16x32_bf16(a1, b, acc[1][nt], 0, 0, 0);
            }
        }
        __syncthreads();
    }

    float biasf[8];
#pragma unroll
    for (int nt = 0; nt < 8; nt++) biasf[nt] = bf2f(bias[nt * 16 + ln]);

#pragma unroll
    for (int mt = 0; mt < 2; mt++) {
        float v[8][4];
#pragma unroll
        for (int nt = 0; nt < 8; nt++)
#pragma unroll
            for (int r = 0; r < 4; r++) {
                float x = acc[mt][nt][r] + biasf[nt];
                v[nt][r] = x > 0.f ? x : 0.f;
            }
        float inv[4];
        if (NORM) {
#pragma unroll
            for (int r = 0; r < 4; r++) {
                float p = 0.f;
#pragma unroll
                for (int nt = 0; nt < 8; nt++) p += v[nt][r] * v[nt][r];
                p += __shfl_xor(p, 1);
                p += __shfl_xor(p, 2);
                p += __shfl_xor(p, 4);
                p += __shfl_xor(p, 8);
                inv[r] = 1.0f / fmaxf(sqrtf(p), 1e-12f);
            }
        }
        int rowbase = blockRow + w * 32 + mt * 16 + q * 4;
#pragma unroll
        for (int r = 0; r < 4; r++) {
            int grow = rowbase + r;
            if (grow < M) {
#pragma unroll
                for (int nt = 0; nt < 8; nt++) {
                    float x = NORM ? v[nt][r] * inv[r] : v[nt][r];
                    Cout[(size_t)grow * 128 + nt * 16 + ln] = f2bf(x);
                }
            }
        }
    }
}

// ---------- CSR mean-aggregate: agg[v] = mean_{e: dst=v} msg[src[e]] ----------
__global__ __launch_bounds__(256) void aggregate_kernel(
    const ushort* __restrict__ msg, const int* __restrict__ rowptr,
    const int* __restrict__ csr_src, ushort* __restrict__ agg, int n) {
    int wid = (int)((blockIdx.x * 256u + threadIdx.x) >> 6);
    int lane = threadIdx.x & 63;
    if (wid >= n) return;
    int start = rowptr[wid], end = rowptr[wid + 1];
    float a0 = 0.f, a1 = 0.f;
#pragma unroll 4
    for (int j = start; j < end; j++) {
        int s = csr_src[j];
        uint v = *(const uint*)(msg + (size_t)s * 128 + lane * 2);
        a0 += bf2f((ushort)(v & 0xffffu));
        a1 += bf2f((ushort)(v >> 16));
    }
    float inv = 1.0f / fmaxf((float)(end - start), 1.0f);
    uint o = (uint)f2bf(a0 * inv) | ((uint)f2bf(a1 * inv) << 16);
    *(uint*)(agg + (size_t)wid * 128 + lane * 2) = o;
}

// ---------- segment max pool (batch sorted; values nonneg -> int atomicMax valid) ----------
__global__ __launch_bounds__(256) void pool_kernel(const ushort* __restrict__ h, const int* __restrict__ batch,
                                                   int* __restrict__ pooled, int n) {
    int d = threadIdx.x & 127;
    int half = threadIdx.x >> 7;
    int start = blockIdx.x * 512;
    int cur_b = -1;
    float cur_max = 0.f;
    for (int i = 0; i < 256; i++) {
        int node = start + half + i * 2;
        if (node >= n) break;
        int b = batch[node];
        float v = bf2f(h[(size_t)node * 128 + d]);
        if (b != cur_b) {
            if (cur_b >= 0) atomicMax(&pooled[cur_b * 128 + d], __float_as_int(cur_max));
            cur_b = b; cur_max = v;
        } else {
            cur_max = fmaxf(cur_max, v);
        }
    }
    if (cur_b >= 0) atomicMax(&pooled[cur_b * 128 + d], __float_as_int(cur_max));
}

// ---------- MLP head + log_softmax (single block); writes out per flag dtype ----------
__global__ __launch_bounds__(256) void final_kernel(const float* __restrict__ pooled,
                                                    const ushort* __restrict__ small,
                                                    void* __restrict__ out, int G,
                                                    const int* __restrict__ flag) {
    __shared__ float T[64 * 128];
    __shared__ float Z[128];
    const ushort* w1 = small + 512;
    const ushort* b1 = small + 16896;
    const ushort* w2 = small + 17024;
    const ushort* b2 = small + 17280;
    int t = threadIdx.x;
    for (int idx = t; idx < G * 128; idx += 256) {
        int g = idx >> 7, j = idx & 127;
        float acc = bf2f(b1[j]);
        for (int k = 0; k < 128; k++) acc += pooled[g * 128 + k] * bf2f(w1[k * 128 + j]);
        T[idx] = acc;
    }
    __syncthreads();
    if (t < G * 2) {
        int g = t >> 1, c = t & 1;
        float acc = bf2f(b2[c]);
        for (int k = 0; k < 128; k++) acc += T[g * 128 + k] * bf2f(w2[k * 2 + c]);
        Z[t] = acc;
    }
    __syncthreads();
    if (t < G) {
        float z0 = Z[2 * t], z1 = Z[2 * t + 1];
        float m = fmaxf(z0, z1);
        float l = m + logf(expf(z0 - m) + expf(z1 - m));
        float o0 = z0 - l, o1 = z1 - l;
        if (*flag) {
            ((float*)out)[2 * t]     = o0;
            ((float*)out)[2 * t + 1] = o1;
        } else {
            ((ushort*)out)[2 * t]     = f2bf(o0);
            ((ushort*)out)[2 * t + 1] = f2bf(o1);
        }
    }
}

extern "C" void kernel_launch(void* const* d_in, const int* in_sizes, int n_in,
                              void* d_out, int out_size, void* d_ws, size_t ws_size,
                              hipStream_t stream) {
    const void* x      = d_in[0];
    const int*  ei     = (const int*)d_in[1];
    const int*  batch  = (const int*)d_in[2];

    const int N = in_sizes[0] / 128;   // 50000 nodes
    const int E = in_sizes[1] / 2;     // 600000 edges
    const int G = out_size / 2;        // 64 graphs
    const int* srcIdx = ei;
    const int* dstIdx = ei + E;

    char* ws = (char*)d_ws;
    size_t off = 0;
    auto alloc = [&](size_t bytes) -> void* {
        off = (off + 255) & ~(size_t)255;
        void* p = ws + off;
        off += bytes;
        return p;
    };
    int*    flag    = (int*)alloc(4);
    int*    deg     = (int*)alloc((size_t)N * 4);
    int*    rowptr  = (int*)alloc((size_t)(N + 1) * 4);
    int*    cursor  = (int*)alloc((size_t)N * 4);
    int*    csr_src = (int*)alloc((size_t)E * 4);
    ushort* Wt0     = (ushort*)alloc(128 * 128 * 2);
    ushort* WtA0    = (ushort*)alloc(256 * 128 * 2);
    ushort* Wt1     = (ushort*)alloc(128 * 128 * 2);
    ushort* WtA1    = (ushort*)alloc(256 * 128 * 2);
    ushort* small   = (ushort*)alloc(17282 * 2);
    ushort* xb      = (ushort*)alloc((size_t)N * 128 * 2);
    ushort* msg     = (ushort*)alloc((size_t)N * 128 * 2);
    ushort* agg     = (ushort*)alloc((size_t)N * 128 * 2);
    ushort* h0      = (ushort*)alloc((size_t)N * 128 * 2);
    int*    pooled  = (int*)alloc((size_t)G * 128 * 4);
    ushort* h1 = msg;  // alias: msg dead once layer-1 aggregate is done

    // dtype sniff + canonicalize everything to bf16
    sniff_kernel<<<1, 256, 0, stream>>>((const uint*)x, flag);
    convert_x<<<(N * 128 + 255) / 256, 256, 0, stream>>>(x, xb, N * 128, flag);
    transpose_all<<<384, 256, 0, stream>>>(d_in[3], d_in[5], d_in[7], d_in[9],
                                           Wt0, WtA0, Wt1, WtA1, flag);
    SmallSrcs ss;
    ss.p[0] = d_in[4];  ss.p[1] = d_in[6];  ss.p[2] = d_in[8];  ss.p[3] = d_in[10];
    ss.p[4] = d_in[11]; ss.p[5] = d_in[12]; ss.p[6] = d_in[13]; ss.p[7] = d_in[14];
    convert_small<<<68, 256, 0, stream>>>(ss, small, flag);

    // CSR build (shared by both layers)
    hipMemsetAsync(deg, 0, (size_t)N * 4, stream);
    int eb = (E + 255) / 256;
    count_deg<<<eb, 256, 0, stream>>>(dstIdx, deg, E);
    scan_kernel<<<1, 256, 0, stream>>>(deg, rowptr, cursor, N);
    fill_kernel<<<eb, 256, 0, stream>>>(srcIdx, dstIdx, cursor, csr_src, E);

    int gb = (N + 127) / 128;
    int ab = (N + 3) / 4;

    // layer 0
    gemm_kernel<1, false><<<gb, 256, 0, stream>>>(xb, xb, Wt0, small + 0, msg, N);
    aggregate_kernel<<<ab, 256, 0, stream>>>(msg, rowptr, csr_src, agg, N);
    gemm_kernel<2, true><<<gb, 256, 0, stream>>>(agg, xb, WtA0, small + 128, h0, N);

    // layer 1
    gemm_kernel<1, false><<<gb, 256, 0, stream>>>(h0, h0, Wt1, small + 256, msg, N);
    aggregate_kernel<<<ab, 256, 0, stream>>>(msg, rowptr, csr_src, agg, N);
    gemm_kernel<2, true><<<gb, 256, 0, stream>>>(agg, h0, WtA1, small + 384, h1, N);

    // pool + head
    hipMemsetAsync(pooled, 0, (size_t)G * 128 * 4, stream);
    pool_kernel<<<(N + 511) / 512, 256, 0, stream>>>(h1, batch, pooled, N);
    final_kernel<<<1, 256, 0, stream>>>((const float*)pooled, small, d_out, G, flag);
}

// Round 3
// 464.740 us; speedup vs baseline: 1.2598x; 1.2598x over previous
//
#include <hip/hip_runtime.h>

// ---------- bf16 helpers (raw ushort representation) ----------
__device__ __forceinline__ float bf2f(ushort u) {
    union { uint i; float f; } c; c.i = ((uint)u) << 16; return c.f;
}
__device__ __forceinline__ ushort f2bf(float f) {
    union { float f; uint i; } c; c.f = f;
    uint b = c.i;
    uint r = (b + 0x7fffu + ((b >> 16) & 1u)) >> 16;
    return (ushort)r;
}

typedef __bf16 v8bf __attribute__((ext_vector_type(8)));
typedef float  v4f  __attribute__((ext_vector_type(4)));

// ---------- dtype sniff: are float inputs f32 (flag=1) or bf16 (flag=0)? ----------
__global__ __launch_bounds__(256) void sniff_kernel(const uint* __restrict__ words, int* __restrict__ flag) {
    __shared__ int s[256];
    int t = threadIdx.x;
    int bad = 0;
    for (int i = t; i < 2048; i += 256) {
        uint w = words[i];
        uint exp = (w >> 7) & 0xffu;   // exponent of low u16 as bf16
        if (exp >= 143u) bad++;        // |val| >= 2^16 -> impossible for sane data
    }
    s[t] = bad;
    __syncthreads();
    for (int o = 128; o; o >>= 1) {
        if (t < o) s[t] += s[t + o];
        __syncthreads();
    }
    if (t == 0) *flag = (s[0] > 64) ? 1 : 0;
}

__device__ __forceinline__ ushort load_conv(const void* src, int i, int isf32) {
    return isf32 ? f2bf(((const float*)src)[i]) : ((const ushort*)src)[i];
}

// ---------- convert x to canonical bf16, 8 elems/thread ----------
__global__ __launch_bounds__(256) void convert_x8(const void* __restrict__ src, ushort* __restrict__ dst,
                                                  int n, const int* __restrict__ flag) {
    int idx = blockIdx.x * 256 + threadIdx.x;
    int base = idx * 8;
    if (base + 8 <= n) {
        if (*flag) {
            const float4* s4 = (const float4*)src;
            float4 a = s4[idx * 2], b = s4[idx * 2 + 1];
            union { ushort u[8]; uint4 v; } o;
            o.u[0] = f2bf(a.x); o.u[1] = f2bf(a.y); o.u[2] = f2bf(a.z); o.u[3] = f2bf(a.w);
            o.u[4] = f2bf(b.x); o.u[5] = f2bf(b.y); o.u[6] = f2bf(b.z); o.u[7] = f2bf(b.w);
            *(uint4*)(dst + base) = o.v;
        } else {
            *(uint4*)(dst + base) = ((const uint4*)src)[idx];
        }
    } else {
        int isf = *flag;
        for (int i = base; i < n; i++) dst[i] = load_conv(src, i, isf);
    }
}

// ---------- small params: 4 biases + mp_w1 + mp_b1 + mp_w2 + mp_b2 ----------
struct SmallSrcs { const void* p[8]; };
// offsets: lin_b0 0, agg_b0 128, lin_b1 256, agg_b1 384, mp_w1 512, mp_b1 16896, mp_w2 17024, mp_b2 17280 (end 17282)
__global__ __launch_bounds__(256) void convert_small(SmallSrcs s, ushort* __restrict__ dst,
                                                     const int* __restrict__ flag) {
    const int offs[9] = {0, 128, 256, 384, 512, 16896, 17024, 17280, 17282};
    int idx = blockIdx.x * 256 + threadIdx.x;
    if (idx >= 17282) return;
    int seg = 0;
    while (idx >= offs[seg + 1]) seg++;
    dst[idx] = load_conv(s.p[seg], idx - offs[seg], *flag);
}

// ---------- transpose the 4 weight matrices (W[K][128] -> Wt[128][K]), flag-aware ----------
__global__ __launch_bounds__(256) void transpose_all(
    const void* __restrict__ w0, const void* __restrict__ wa0,
    const void* __restrict__ w1, const void* __restrict__ wa1,
    ushort* __restrict__ t0, ushort* __restrict__ ta0,
    ushort* __restrict__ t1, ushort* __restrict__ ta1,
    const int* __restrict__ flag) {
    int idx = blockIdx.x * 256 + threadIdx.x;   // 0 .. 98303
    const void* W; ushort* T; int K; int local;
    if (idx < 16384)      { W = w0;  T = t0;  K = 128; local = idx; }
    else if (idx < 49152) { W = wa0; T = ta0; K = 256; local = idx - 16384; }
    else if (idx < 65536) { W = w1;  T = t1;  K = 128; local = idx - 49152; }
    else                  { W = wa1; T = ta1; K = 256; local = idx - 65536; }
    ushort v = load_conv(W, local, *flag);
    int k = local >> 7;       // row in W
    int n = local & 127;      // col in W
    T[(size_t)n * K + k] = v;
}

// ---------- CSR build ----------
__global__ __launch_bounds__(256) void count_deg(const int* __restrict__ dst, int* __restrict__ deg, int E) {
    int i = blockIdx.x * 256 + threadIdx.x;
    if (i < E) atomicAdd(&deg[dst[i]], 1);
}

// multi-block exclusive scan, CHUNK=1024 elems per block
#define SCAN_CHUNK 1024

__global__ __launch_bounds__(256) void chunk_sum_kernel(const int* __restrict__ deg,
                                                        int* __restrict__ csums, int n) {
    __shared__ int s[256];
    int t = threadIdx.x;
    int base = blockIdx.x * SCAN_CHUNK + t * 4;
    int v = 0;
    if (base + 4 <= n) {
        int4 q = *(const int4*)(deg + base);
        v = q.x + q.y + q.z + q.w;
    } else {
        for (int i = base; i < n; i++) v += deg[i];
    }
    s[t] = v;
    __syncthreads();
    for (int o = 128; o; o >>= 1) {
        if (t < o) s[t] += s[t + o];
        __syncthreads();
    }
    if (t == 0) csums[blockIdx.x] = s[0];
}

// block b: offset = sum(csums[0..b)), then 256-wide scan of 4-elem sums; writes rowptr+cursor
// one thread's quad straddles n -> writes rowptr[n] = E
__global__ __launch_bounds__(256) void scan_phase2(const int* __restrict__ deg,
                                                   const int* __restrict__ csums,
                                                   int* __restrict__ rowptr, int* __restrict__ cursor,
                                                   int n) {
    __shared__ int red[256];
    int t = threadIdx.x, b = blockIdx.x;
    // chunk offset
    int v = 0;
    for (int i = t; i < b; i += 256) v += csums[i];
    red[t] = v;
    __syncthreads();
    for (int o = 128; o; o >>= 1) {
        if (t < o) red[t] += red[t + o];
        __syncthreads();
    }
    int chunkOff = red[0];
    __syncthreads();
    // load this thread's 4 elems
    int base = b * SCAN_CHUNK + t * 4;
    int d0 = 0, d1 = 0, d2 = 0, d3 = 0;
    if (base + 4 <= n) {
        int4 q = *(const int4*)(deg + base);
        d0 = q.x; d1 = q.y; d2 = q.z; d3 = q.w;
    } else {
        if (base < n)     d0 = deg[base];
        if (base + 1 < n) d1 = deg[base + 1];
        if (base + 2 < n) d2 = deg[base + 2];
        if (base + 3 < n) d3 = deg[base + 3];
    }
    int s4 = d0 + d1 + d2 + d3;
    // Hillis-Steele inclusive scan of s4
    red[t] = s4;
    __syncthreads();
    for (int o = 1; o < 256; o <<= 1) {
        int u = (t >= o) ? red[t - o] : 0;
        __syncthreads();
        red[t] += u;
        __syncthreads();
    }
    int run = chunkOff + red[t] - s4;  // exclusive prefix at base
    if (base < n)     { rowptr[base]     = run; cursor[base]     = run; run += d0; }
    if (base + 1 < n) { rowptr[base + 1] = run; cursor[base + 1] = run; run += d1; }
    if (base + 2 < n) { rowptr[base + 2] = run; cursor[base + 2] = run; run += d2; }
    if (base + 3 < n) { rowptr[base + 3] = run; cursor[base + 3] = run; run += d3; }
    if (n >= base && n < base + 4) rowptr[n] = run;  // exactly one thread grid-wide
}

__global__ __launch_bounds__(256) void fill_kernel(const int* __restrict__ src, const int* __restrict__ dst,
                                                   int* __restrict__ cursor, int* __restrict__ csr_src, int E) {
    int i = blockIdx.x * 256 + threadIdx.x;
    if (i < E) {
        int pos = atomicAdd(&cursor[dst[i]], 1);
        csr_src[pos] = src[i];
    }
}

// ---------- MFMA GEMM: C[M][128] = relu(A @ Bt^T + bias), optional row-L2-normalize ----------
template <int NSTAGE, bool NORM>
__global__ __launch_bounds__(256) void gemm_kernel(
    const ushort* __restrict__ A0, const ushort* __restrict__ A1,
    const ushort* __restrict__ Bt, const ushort* __restrict__ bias,
    ushort* __restrict__ Cout, int M) {
    __shared__ __bf16 As[128 * 72];  // 64 k-chunk, stride 72 (pad 8)
    __shared__ __bf16 Bs[128 * 72];
    const int t = threadIdx.x;
    const int w = t >> 6, lane = t & 63, ln = lane & 15, q = lane >> 4;
    const int blockRow = blockIdx.x * 128;
    const int K = NSTAGE * 128;

    v4f acc[2][8];
#pragma unroll
    for (int i = 0; i < 2; i++)
#pragma unroll
        for (int j = 0; j < 8; j++) acc[i][j] = (v4f){0.f, 0.f, 0.f, 0.f};

    for (int kc = 0; kc < K; kc += 64) {
        const ushort* Ap = (kc < 128) ? A0 : A1;
        int kin = kc & 127;
#pragma unroll
        for (int i = 0; i < 4; i++) {
            int c = i * 256 + t;
            int row = c >> 3, c8 = c & 7;
            int grow = blockRow + row; if (grow >= M) grow = M - 1;
            *(uint4*)&As[row * 72 + c8 * 8] = *(const uint4*)(Ap + (size_t)grow * 128 + kin + c8 * 8);
            *(uint4*)&Bs[row * 72 + c8 * 8] = *(const uint4*)(Bt + (size_t)row * K + kc + c8 * 8);
        }
        __syncthreads();
#pragma unroll
        for (int k0 = 0; k0 < 64; k0 += 32) {
            v8bf a0 = *(const v8bf*)&As[(w * 32 + ln) * 72 + k0 + q * 8];
            v8bf a1 = *(const v8bf*)&As[(w * 32 + 16 + ln) * 72 + k0 + q * 8];
#pragma unroll
            for (int nt = 0; nt < 8; nt++) {
                v8bf b = *(const v8bf*)&Bs[(nt * 16 + ln) * 72 + k0 + q * 8];
                acc[0][nt] = __builtin_amdgcn_mfma_f32_16x16x32_bf16(a0, b, acc[0][nt], 0, 0, 0);
                acc[1][nt] = __builtin_amdgcn_mfma_f32_16x16x32_bf16(a1, b, acc[1][nt], 0, 0, 0);
            }
        }
        __syncthreads();
    }

    float biasf[8];
#pragma unroll
    for (int nt = 0; nt < 8; nt++) biasf[nt] = bf2f(bias[nt * 16 + ln]);

#pragma unroll
    for (int mt = 0; mt < 2; mt++) {
        float v[8][4];
#pragma unroll
        for (int nt = 0; nt < 8; nt++)
#pragma unroll
            for (int r = 0; r < 4; r++) {
                float x = acc[mt][nt][r] + biasf[nt];
                v[nt][r] = x > 0.f ? x : 0.f;
            }
        float inv[4];
        if (NORM) {
#pragma unroll
            for (int r = 0; r < 4; r++) {
                float p = 0.f;
#pragma unroll
                for (int nt = 0; nt < 8; nt++) p += v[nt][r] * v[nt][r];
                p += __shfl_xor(p, 1);
                p += __shfl_xor(p, 2);
                p += __shfl_xor(p, 4);
                p += __shfl_xor(p, 8);
                inv[r] = 1.0f / fmaxf(sqrtf(p), 1e-12f);
            }
        }
        int rowbase = blockRow + w * 32 + mt * 16 + q * 4;
#pragma unroll
        for (int r = 0; r < 4; r++) {
            int grow = rowbase + r;
            if (grow < M) {
#pragma unroll
                for (int nt = 0; nt < 8; nt++) {
                    float x = NORM ? v[nt][r] * inv[r] : v[nt][r];
                    Cout[(size_t)grow * 128 + nt * 16 + ln] = f2bf(x);
                }
            }
        }
    }
}

// ---------- CSR mean-aggregate: agg[v] = mean_{e: dst=v} msg[src[e]] ----------
__global__ __launch_bounds__(256) void aggregate_kernel(
    const ushort* __restrict__ msg, const int* __restrict__ rowptr,
    const int* __restrict__ csr_src, ushort* __restrict__ agg, int n) {
    int wid = (int)((blockIdx.x * 256u + threadIdx.x) >> 6);
    int lane = threadIdx.x & 63;
    if (wid >= n) return;
    int start = rowptr[wid], end = rowptr[wid + 1];
    float a0 = 0.f, a1 = 0.f;
#pragma unroll 4
    for (int j = start; j < end; j++) {
        int s = csr_src[j];
        uint v = *(const uint*)(msg + (size_t)s * 128 + lane * 2);
        a0 += bf2f((ushort)(v & 0xffffu));
        a1 += bf2f((ushort)(v >> 16));
    }
    float inv = 1.0f / fmaxf((float)(end - start), 1.0f);
    uint o = (uint)f2bf(a0 * inv) | ((uint)f2bf(a1 * inv) << 16);
    *(uint*)(agg + (size_t)wid * 128 + lane * 2) = o;
}

// ---------- segment max pool (batch sorted; values nonneg -> int atomicMax valid) ----------
// block covers 128 nodes: two halves of the block interleave over them
__global__ __launch_bounds__(256) void pool_kernel(const ushort* __restrict__ h, const int* __restrict__ batch,
                                                   int* __restrict__ pooled, int n) {
    int d = threadIdx.x & 127;
    int half = threadIdx.x >> 7;
    int start = blockIdx.x * 128;
    int cur_b = -1;
    float cur_max = 0.f;
    for (int i = 0; i < 64; i++) {
        int node = start + half + i * 2;
        if (node >= n) break;
        int b = batch[node];
        float v = bf2f(h[(size_t)node * 128 + d]);
        if (b != cur_b) {
            if (cur_b >= 0) atomicMax(&pooled[cur_b * 128 + d], __float_as_int(cur_max));
            cur_b = b; cur_max = v;
        } else {
            cur_max = fmaxf(cur_max, v);
        }
    }
    if (cur_b >= 0) atomicMax(&pooled[cur_b * 128 + d], __float_as_int(cur_max));
}

// ---------- MLP head + log_softmax (single block); writes out per flag dtype ----------
__global__ __launch_bounds__(256) void final_kernel(const float* __restrict__ pooled,
                                                    const ushort* __restrict__ small,
                                                    void* __restrict__ out, int G,
                                                    const int* __restrict__ flag) {
    __shared__ float T[64 * 128];
    __shared__ float Z[128];
    const ushort* w1 = small + 512;
    const ushort* b1 = small + 16896;
    const ushort* w2 = small + 17024;
    const ushort* b2 = small + 17280;
    int t = threadIdx.x;
    for (int idx = t; idx < G * 128; idx += 256) {
        int g = idx >> 7, j = idx & 127;
        float acc = bf2f(b1[j]);
#pragma unroll 4
        for (int k = 0; k < 128; k++) acc += pooled[g * 128 + k] * bf2f(w1[k * 128 + j]);
        T[idx] = acc;
    }
    __syncthreads();
    if (t < G * 2) {
        int g = t >> 1, c = t & 1;
        float acc = bf2f(b2[c]);
#pragma unroll 4
        for (int k = 0; k < 128; k++) acc += T[g * 128 + k] * bf2f(w2[k * 2 + c]);
        Z[t] = acc;
    }
    __syncthreads();
    if (t < G) {
        float z0 = Z[2 * t], z1 = Z[2 * t + 1];
        float m = fmaxf(z0, z1);
        float l = m + logf(expf(z0 - m) + expf(z1 - m));
        float o0 = z0 - l, o1 = z1 - l;
        if (*flag) {
            ((float*)out)[2 * t]     = o0;
            ((float*)out)[2 * t + 1] = o1;
        } else {
            ((ushort*)out)[2 * t]     = f2bf(o0);
            ((ushort*)out)[2 * t + 1] = f2bf(o1);
        }
    }
}

extern "C" void kernel_launch(void* const* d_in, const int* in_sizes, int n_in,
                              void* d_out, int out_size, void* d_ws, size_t ws_size,
                              hipStream_t stream) {
    const void* x      = d_in[0];
    const int*  ei     = (const int*)d_in[1];
    const int*  batch  = (const int*)d_in[2];

    const int N = in_sizes[0] / 128;   // 50000 nodes
    const int E = in_sizes[1] / 2;     // 600000 edges
    const int G = out_size / 2;        // 64 graphs
    const int* srcIdx = ei;
    const int* dstIdx = ei + E;

    char* ws = (char*)d_ws;
    size_t off = 0;
    auto alloc = [&](size_t bytes) -> void* {
        off = (off + 255) & ~(size_t)255;
        void* p = ws + off;
        off += bytes;
        return p;
    };
    int*    flag    = (int*)alloc(4);
    int*    deg     = (int*)alloc((size_t)N * 4);
    int*    rowptr  = (int*)alloc((size_t)(N + 1) * 4);
    int*    cursor  = (int*)alloc((size_t)N * 4);
    int*    csr_src = (int*)alloc((size_t)E * 4);
    int*    csums   = (int*)alloc(((size_t)N / SCAN_CHUNK + 2) * 4);
    ushort* Wt0     = (ushort*)alloc(128 * 128 * 2);
    ushort* WtA0    = (ushort*)alloc(256 * 128 * 2);
    ushort* Wt1     = (ushort*)alloc(128 * 128 * 2);
    ushort* WtA1    = (ushort*)alloc(256 * 128 * 2);
    ushort* small   = (ushort*)alloc(17282 * 2);
    ushort* xb      = (ushort*)alloc((size_t)N * 128 * 2);
    ushort* msg     = (ushort*)alloc((size_t)N * 128 * 2);
    ushort* agg     = (ushort*)alloc((size_t)N * 128 * 2);
    ushort* h0      = (ushort*)alloc((size_t)N * 128 * 2);
    int*    pooled  = (int*)alloc((size_t)G * 128 * 4);
    ushort* h1 = msg;  // alias: msg dead once layer-1 aggregate is done

    // dtype sniff + canonicalize everything to bf16
    sniff_kernel<<<1, 256, 0, stream>>>((const uint*)x, flag);
    convert_x8<<<(N * 128 + 2047) / 2048, 256, 0, stream>>>(x, xb, N * 128, flag);
    transpose_all<<<384, 256, 0, stream>>>(d_in[3], d_in[5], d_in[7], d_in[9],
                                           Wt0, WtA0, Wt1, WtA1, flag);
    SmallSrcs ss;
    ss.p[0] = d_in[4];  ss.p[1] = d_in[6];  ss.p[2] = d_in[8];  ss.p[3] = d_in[10];
    ss.p[4] = d_in[11]; ss.p[5] = d_in[12]; ss.p[6] = d_in[13]; ss.p[7] = d_in[14];
    convert_small<<<68, 256, 0, stream>>>(ss, small, flag);

    // CSR build (shared by both layers)
    hipMemsetAsync(deg, 0, (size_t)N * 4, stream);
    int eb = (E + 255) / 256;
    count_deg<<<eb, 256, 0, stream>>>(dstIdx, deg, E);
    int nchunks = (N + SCAN_CHUNK - 1) / SCAN_CHUNK;
    chunk_sum_kernel<<<nchunks, 256, 0, stream>>>(deg, csums, N);
    scan_phase2<<<N / SCAN_CHUNK + 1, 256, 0, stream>>>(deg, csums, rowptr, cursor, N);
    fill_kernel<<<eb, 256, 0, stream>>>(srcIdx, dstIdx, cursor, csr_src, E);

    int gb = (N + 127) / 128;
    int ab = (N + 3) / 4;

    // layer 0
    gemm_kernel<1, false><<<gb, 256, 0, stream>>>(xb, xb, Wt0, small + 0, msg, N);
    aggregate_kernel<<<ab, 256, 0, stream>>>(msg, rowptr, csr_src, agg, N);
    gemm_kernel<2, true><<<gb, 256, 0, stream>>>(agg, xb, WtA0, small + 128, h0, N);

    // layer 1
    gemm_kernel<1, false><<<gb, 256, 0, stream>>>(h0, h0, Wt1, small + 256, msg, N);
    aggregate_kernel<<<ab, 256, 0, stream>>>(msg, rowptr, csr_src, agg, N);
    gemm_kernel<2, true><<<gb, 256, 0, stream>>>(agg, h0, WtA1, small + 384, h1, N);

    // pool + head
    hipMemsetAsync(pooled, 0, (size_t)G * 128 * 4, stream);
    pool_kernel<<<(N + 127) / 128, 256, 0, stream>>>(h1, batch, pooled, N);
    final_kernel<<<1, 256, 0, stream>>>((const float*)pooled, small, d_out, G, flag);
}

// Round 4
// 324.288 us; speedup vs baseline: 1.8055x; 1.4331x over previous
//
#include <hip/hip_runtime.h>

// ---------- bf16 helpers (raw ushort representation) ----------
__device__ __forceinline__ float bf2f(ushort u) {
    union { uint i; float f; } c; c.i = ((uint)u) << 16; return c.f;
}
__device__ __forceinline__ ushort f2bf(float f) {
    union { float f; uint i; } c; c.f = f;
    uint b = c.i;
    uint r = (b + 0x7fffu + ((b >> 16) & 1u)) >> 16;
    return (ushort)r;
}

typedef __bf16 v8bf __attribute__((ext_vector_type(8)));
typedef float  v4f  __attribute__((ext_vector_type(4)));

// ---------- dtype sniff: are float inputs f32 (flag=1) or bf16 (flag=0)? ----------
__global__ __launch_bounds__(256) void sniff_kernel(const uint* __restrict__ words, int* __restrict__ flag) {
    __shared__ int s[256];
    int t = threadIdx.x;
    int bad = 0;
    for (int i = t; i < 2048; i += 256) {
        uint w = words[i];
        uint exp = (w >> 7) & 0xffu;   // exponent of low u16 as bf16
        if (exp >= 143u) bad++;        // |val| >= 2^16 -> impossible for sane data
    }
    s[t] = bad;
    __syncthreads();
    for (int o = 128; o; o >>= 1) {
        if (t < o) s[t] += s[t + o];
        __syncthreads();
    }
    if (t == 0) *flag = (s[0] > 64) ? 1 : 0;
}

__device__ __forceinline__ ushort load_conv(const void* src, int i, int isf32) {
    return isf32 ? f2bf(((const float*)src)[i]) : ((const ushort*)src)[i];
}

// ---------- convert x to canonical bf16, 8 elems/thread ----------
__global__ __launch_bounds__(256) void convert_x8(const void* __restrict__ src, ushort* __restrict__ dst,
                                                  int n, const int* __restrict__ flag) {
    int idx = blockIdx.x * 256 + threadIdx.x;
    int base = idx * 8;
    if (base + 8 <= n) {
        if (*flag) {
            const float4* s4 = (const float4*)src;
            float4 a = s4[idx * 2], b = s4[idx * 2 + 1];
            union { ushort u[8]; uint4 v; } o;
            o.u[0] = f2bf(a.x); o.u[1] = f2bf(a.y); o.u[2] = f2bf(a.z); o.u[3] = f2bf(a.w);
            o.u[4] = f2bf(b.x); o.u[5] = f2bf(b.y); o.u[6] = f2bf(b.z); o.u[7] = f2bf(b.w);
            *(uint4*)(dst + base) = o.v;
        } else {
            *(uint4*)(dst + base) = ((const uint4*)src)[idx];
        }
    } else {
        int isf = *flag;
        for (int i = base; i < n; i++) dst[i] = load_conv(src, i, isf);
    }
}

// ---------- small params: 4 biases + mp_w1 + mp_b1 + mp_w2 + mp_b2 ----------
struct SmallSrcs { const void* p[8]; };
// offsets: lin_b0 0, agg_b0 128, lin_b1 256, agg_b1 384, mp_w1 512, mp_b1 16896, mp_w2 17024, mp_b2 17280 (end 17282)
__global__ __launch_bounds__(256) void convert_small(SmallSrcs s, ushort* __restrict__ dst,
                                                     const int* __restrict__ flag) {
    const int offs[9] = {0, 128, 256, 384, 512, 16896, 17024, 17280, 17282};
    int idx = blockIdx.x * 256 + threadIdx.x;
    if (idx >= 17282) return;
    int seg = 0;
    while (idx >= offs[seg + 1]) seg++;
    dst[idx] = load_conv(s.p[seg], idx - offs[seg], *flag);
}

// ---------- transpose the 4 weight matrices (W[K][128] -> Wt[128][K]), flag-aware ----------
__global__ __launch_bounds__(256) void transpose_all(
    const void* __restrict__ w0, const void* __restrict__ wa0,
    const void* __restrict__ w1, const void* __restrict__ wa1,
    ushort* __restrict__ t0, ushort* __restrict__ ta0,
    ushort* __restrict__ t1, ushort* __restrict__ ta1,
    const int* __restrict__ flag) {
    int idx = blockIdx.x * 256 + threadIdx.x;   // 0 .. 98303
    const void* W; ushort* T; int K; int local;
    if (idx < 16384)      { W = w0;  T = t0;  K = 128; local = idx; }
    else if (idx < 49152) { W = wa0; T = ta0; K = 256; local = idx - 16384; }
    else if (idx < 65536) { W = w1;  T = t1;  K = 128; local = idx - 49152; }
    else                  { W = wa1; T = ta1; K = 256; local = idx - 65536; }
    ushort v = load_conv(W, local, *flag);
    int k = local >> 7;       // row in W
    int n = local & 127;      // col in W
    T[(size_t)n * K + k] = v;
}

// ---------- CSR build ----------
__global__ __launch_bounds__(256) void count_deg(const int* __restrict__ dst, int* __restrict__ deg, int E) {
    int i = blockIdx.x * 256 + threadIdx.x;
    if (i < E) atomicAdd(&deg[dst[i]], 1);
}

// multi-block exclusive scan, CHUNK=1024 elems per block
#define SCAN_CHUNK 1024

__global__ __launch_bounds__(256) void chunk_sum_kernel(const int* __restrict__ deg,
                                                        int* __restrict__ csums, int n) {
    __shared__ int s[256];
    int t = threadIdx.x;
    int base = blockIdx.x * SCAN_CHUNK + t * 4;
    int v = 0;
    if (base + 4 <= n) {
        int4 q = *(const int4*)(deg + base);
        v = q.x + q.y + q.z + q.w;
    } else {
        for (int i = base; i < n; i++) v += deg[i];
    }
    s[t] = v;
    __syncthreads();
    for (int o = 128; o; o >>= 1) {
        if (t < o) s[t] += s[t + o];
        __syncthreads();
    }
    if (t == 0) csums[blockIdx.x] = s[0];
}

// block b: offset = sum(csums[0..b)), then 256-wide scan of 4-elem sums; writes rowptr+cursor
__global__ __launch_bounds__(256) void scan_phase2(const int* __restrict__ deg,
                                                   const int* __restrict__ csums,
                                                   int* __restrict__ rowptr, int* __restrict__ cursor,
                                                   int n) {
    __shared__ int red[256];
    int t = threadIdx.x, b = blockIdx.x;
    int v = 0;
    for (int i = t; i < b; i += 256) v += csums[i];
    red[t] = v;
    __syncthreads();
    for (int o = 128; o; o >>= 1) {
        if (t < o) red[t] += red[t + o];
        __syncthreads();
    }
    int chunkOff = red[0];
    __syncthreads();
    int base = b * SCAN_CHUNK + t * 4;
    int d0 = 0, d1 = 0, d2 = 0, d3 = 0;
    if (base + 4 <= n) {
        int4 q = *(const int4*)(deg + base);
        d0 = q.x; d1 = q.y; d2 = q.z; d3 = q.w;
    } else {
        if (base < n)     d0 = deg[base];
        if (base + 1 < n) d1 = deg[base + 1];
        if (base + 2 < n) d2 = deg[base + 2];
        if (base + 3 < n) d3 = deg[base + 3];
    }
    int s4 = d0 + d1 + d2 + d3;
    red[t] = s4;
    __syncthreads();
    for (int o = 1; o < 256; o <<= 1) {
        int u = (t >= o) ? red[t - o] : 0;
        __syncthreads();
        red[t] += u;
        __syncthreads();
    }
    int run = chunkOff + red[t] - s4;  // exclusive prefix at base
    if (base < n)     { rowptr[base]     = run; cursor[base]     = run; run += d0; }
    if (base + 1 < n) { rowptr[base + 1] = run; cursor[base + 1] = run; run += d1; }
    if (base + 2 < n) { rowptr[base + 2] = run; cursor[base + 2] = run; run += d2; }
    if (base + 3 < n) { rowptr[base + 3] = run; cursor[base + 3] = run; run += d3; }
    if (n >= base && n < base + 4) rowptr[n] = run;  // exactly one thread grid-wide
}

__global__ __launch_bounds__(256) void fill_kernel(const int* __restrict__ src, const int* __restrict__ dst,
                                                   int* __restrict__ cursor, int* __restrict__ csr_src, int E) {
    int i = blockIdx.x * 256 + threadIdx.x;
    if (i < E) {
        int pos = atomicAdd(&cursor[dst[i]], 1);
        csr_src[pos] = src[i];
    }
}

// ---------- MFMA GEMM: C[M][128] = relu(A @ Bt^T + bias), optional row-L2-normalize ----------
template <int NSTAGE, bool NORM>
__global__ __launch_bounds__(256) void gemm_kernel(
    const ushort* __restrict__ A0, const ushort* __restrict__ A1,
    const ushort* __restrict__ Bt, const ushort* __restrict__ bias,
    ushort* __restrict__ Cout, int M) {
    __shared__ __bf16 As[128 * 72];  // 64 k-chunk, stride 72 (pad 8)
    __shared__ __bf16 Bs[128 * 72];
    const int t = threadIdx.x;
    const int w = t >> 6, lane = t & 63, ln = lane & 15, q = lane >> 4;
    const int blockRow = blockIdx.x * 128;
    const int K = NSTAGE * 128;

    v4f acc[2][8];
#pragma unroll
    for (int i = 0; i < 2; i++)
#pragma unroll
        for (int j = 0; j < 8; j++) acc[i][j] = (v4f){0.f, 0.f, 0.f, 0.f};

    for (int kc = 0; kc < K; kc += 64) {
        const ushort* Ap = (kc < 128) ? A0 : A1;
        int kin = kc & 127;
#pragma unroll
        for (int i = 0; i < 4; i++) {
            int c = i * 256 + t;
            int row = c >> 3, c8 = c & 7;
            int grow = blockRow + row; if (grow >= M) grow = M - 1;
            *(uint4*)&As[row * 72 + c8 * 8] = *(const uint4*)(Ap + (size_t)grow * 128 + kin + c8 * 8);
            *(uint4*)&Bs[row * 72 + c8 * 8] = *(const uint4*)(Bt + (size_t)row * K + kc + c8 * 8);
        }
        __syncthreads();
#pragma unroll
        for (int k0 = 0; k0 < 64; k0 += 32) {
            v8bf a0 = *(const v8bf*)&As[(w * 32 + ln) * 72 + k0 + q * 8];
            v8bf a1 = *(const v8bf*)&As[(w * 32 + 16 + ln) * 72 + k0 + q * 8];
#pragma unroll
            for (int nt = 0; nt < 8; nt++) {
                v8bf b = *(const v8bf*)&Bs[(nt * 16 + ln) * 72 + k0 + q * 8];
                acc[0][nt] = __builtin_amdgcn_mfma_f32_16x16x32_bf16(a0, b, acc[0][nt], 0, 0, 0);
                acc[1][nt] = __builtin_amdgcn_mfma_f32_16x16x32_bf16(a1, b, acc[1][nt], 0, 0, 0);
            }
        }
        __syncthreads();
    }

    float biasf[8];
#pragma unroll
    for (int nt = 0; nt < 8; nt++) biasf[nt] = bf2f(bias[nt * 16 + ln]);

#pragma unroll
    for (int mt = 0; mt < 2; mt++) {
        float v[8][4];
#pragma unroll
        for (int nt = 0; nt < 8; nt++)
#pragma unroll
            for (int r = 0; r < 4; r++) {
                float x = acc[mt][nt][r] + biasf[nt];
                v[nt][r] = x > 0.f ? x : 0.f;
            }
        float inv[4];
        if (NORM) {
#pragma unroll
            for (int r = 0; r < 4; r++) {
                float p = 0.f;
#pragma unroll
                for (int nt = 0; nt < 8; nt++) p += v[nt][r] * v[nt][r];
                p += __shfl_xor(p, 1);
                p += __shfl_xor(p, 2);
                p += __shfl_xor(p, 4);
                p += __shfl_xor(p, 8);
                inv[r] = 1.0f / fmaxf(sqrtf(p), 1e-12f);
            }
        }
        int rowbase = blockRow + w * 32 + mt * 16 + q * 4;
#pragma unroll
        for (int r = 0; r < 4; r++) {
            int grow = rowbase + r;
            if (grow < M) {
#pragma unroll
                for (int nt = 0; nt < 8; nt++) {
                    float x = NORM ? v[nt][r] * inv[r] : v[nt][r];
                    Cout[(size_t)grow * 128 + nt * 16 + ln] = f2bf(x);
                }
            }
        }
    }
}

// ---------- CSR mean-aggregate: agg[v] = mean_{e: dst=v} msg[src[e]] ----------
__global__ __launch_bounds__(256) void aggregate_kernel(
    const ushort* __restrict__ msg, const int* __restrict__ rowptr,
    const int* __restrict__ csr_src, ushort* __restrict__ agg, int n) {
    int wid = (int)((blockIdx.x * 256u + threadIdx.x) >> 6);
    int lane = threadIdx.x & 63;
    if (wid >= n) return;
    int start = rowptr[wid], end = rowptr[wid + 1];
    float a0 = 0.f, a1 = 0.f;
#pragma unroll 4
    for (int j = start; j < end; j++) {
        int s = csr_src[j];
        uint v = *(const uint*)(msg + (size_t)s * 128 + lane * 2);
        a0 += bf2f((ushort)(v & 0xffffu));
        a1 += bf2f((ushort)(v >> 16));
    }
    float inv = 1.0f / fmaxf((float)(end - start), 1.0f);
    uint o = (uint)f2bf(a0 * inv) | ((uint)f2bf(a1 * inv) << 16);
    *(uint*)(agg + (size_t)wid * 128 + lane * 2) = o;
}

// ---------- segment max pool (batch sorted; values nonneg -> int atomicMax valid) ----------
__global__ __launch_bounds__(256) void pool_kernel(const ushort* __restrict__ h, const int* __restrict__ batch,
                                                   int* __restrict__ pooled, int n) {
    int d = threadIdx.x & 127;
    int half = threadIdx.x >> 7;
    int start = blockIdx.x * 128;
    int cur_b = -1;
    float cur_max = 0.f;
    for (int i = 0; i < 64; i++) {
        int node = start + half + i * 2;
        if (node >= n) break;
        int b = batch[node];
        float v = bf2f(h[(size_t)node * 128 + d]);
        if (b != cur_b) {
            if (cur_b >= 0) atomicMax(&pooled[cur_b * 128 + d], __float_as_int(cur_max));
            cur_b = b; cur_max = v;
        } else {
            cur_max = fmaxf(cur_max, v);
        }
    }
    if (cur_b >= 0) atomicMax(&pooled[cur_b * 128 + d], __float_as_int(cur_max));
}

// ---------- MLP head + log_softmax: ONE BLOCK PER GRAPH ----------
__global__ __launch_bounds__(256) void final_kernel(const float* __restrict__ pooled,
                                                    const ushort* __restrict__ small,
                                                    void* __restrict__ out, int G,
                                                    const int* __restrict__ flag) {
    __shared__ float P[128];
    __shared__ float Thalf[128];
    __shared__ float T[128];
    __shared__ float R0[128], R1[128];
    const ushort* w1 = small + 512;
    const ushort* b1 = small + 16896;
    const ushort* w2 = small + 17024;
    const ushort* b2 = small + 17280;
    int g = blockIdx.x;
    int t = threadIdx.x;
    int j = t & 127, half = t >> 7;
    if (t < 128) P[t] = pooled[g * 128 + t];
    __syncthreads();
    // T[j] = b1[j] + sum_k P[k] * w1[k][j], split over two K-halves
    float acc = 0.f;
    int k0 = half * 64;
#pragma unroll 8
    for (int k = k0; k < k0 + 64; k++) acc += P[k] * bf2f(w1[k * 128 + j]);
    if (half == 0) Thalf[j] = acc;
    __syncthreads();
    if (half == 1) T[j] = Thalf[j] + acc + bf2f(b1[j]);
    __syncthreads();
    // logits: z[c] = b2[c] + sum_j T[j] * w2[j][c]
    if (t < 128) {
        float tv = T[t];
        R0[t] = tv * bf2f(w2[t * 2]);
        R1[t] = tv * bf2f(w2[t * 2 + 1]);
    }
    __syncthreads();
    for (int o = 64; o; o >>= 1) {
        if (t < o) { R0[t] += R0[t + o]; R1[t] += R1[t + o]; }
        __syncthreads();
    }
    if (t == 0) {
        float z0 = R0[0] + bf2f(b2[0]);
        float z1 = R1[0] + bf2f(b2[1]);
        float m = fmaxf(z0, z1);
        float l = m + logf(expf(z0 - m) + expf(z1 - m));
        float o0 = z0 - l, o1 = z1 - l;
        if (*flag) {
            ((float*)out)[2 * g]     = o0;
            ((float*)out)[2 * g + 1] = o1;
        } else {
            ((ushort*)out)[2 * g]     = f2bf(o0);
            ((ushort*)out)[2 * g + 1] = f2bf(o1);
        }
    }
}

extern "C" void kernel_launch(void* const* d_in, const int* in_sizes, int n_in,
                              void* d_out, int out_size, void* d_ws, size_t ws_size,
                              hipStream_t stream) {
    const void* x      = d_in[0];
    const int*  ei     = (const int*)d_in[1];
    const int*  batch  = (const int*)d_in[2];

    const int N = in_sizes[0] / 128;   // 50000 nodes
    const int E = in_sizes[1] / 2;     // 600000 edges
    const int G = out_size / 2;        // 64 graphs
    const int* srcIdx = ei;
    const int* dstIdx = ei + E;

    char* ws = (char*)d_ws;
    size_t off = 0;
    auto alloc = [&](size_t bytes) -> void* {
        off = (off + 255) & ~(size_t)255;
        void* p = ws + off;
        off += bytes;
        return p;
    };
    int*    flag    = (int*)alloc(4);
    int*    deg     = (int*)alloc((size_t)N * 4);
    int*    rowptr  = (int*)alloc((size_t)(N + 1) * 4);
    int*    cursor  = (int*)alloc((size_t)N * 4);
    int*    csr_src = (int*)alloc((size_t)E * 4);
    int*    csums   = (int*)alloc(((size_t)N / SCAN_CHUNK + 2) * 4);
    ushort* Wt0     = (ushort*)alloc(128 * 128 * 2);
    ushort* WtA0    = (ushort*)alloc(256 * 128 * 2);
    ushort* Wt1     = (ushort*)alloc(128 * 128 * 2);
    ushort* WtA1    = (ushort*)alloc(256 * 128 * 2);
    ushort* small   = (ushort*)alloc(17282 * 2);
    ushort* xb      = (ushort*)alloc((size_t)N * 128 * 2);
    ushort* msg     = (ushort*)alloc((size_t)N * 128 * 2);
    ushort* agg     = (ushort*)alloc((size_t)N * 128 * 2);
    ushort* h0      = (ushort*)alloc((size_t)N * 128 * 2);
    int*    pooled  = (int*)alloc((size_t)G * 128 * 4);
    ushort* h1 = msg;  // alias: msg dead once layer-1 aggregate is done

    // dtype sniff + canonicalize everything to bf16
    sniff_kernel<<<1, 256, 0, stream>>>((const uint*)x, flag);
    convert_x8<<<(N * 128 + 2047) / 2048, 256, 0, stream>>>(x, xb, N * 128, flag);
    transpose_all<<<384, 256, 0, stream>>>(d_in[3], d_in[5], d_in[7], d_in[9],
                                           Wt0, WtA0, Wt1, WtA1, flag);
    SmallSrcs ss;
    ss.p[0] = d_in[4];  ss.p[1] = d_in[6];  ss.p[2] = d_in[8];  ss.p[3] = d_in[10];
    ss.p[4] = d_in[11]; ss.p[5] = d_in[12]; ss.p[6] = d_in[13]; ss.p[7] = d_in[14];
    convert_small<<<68, 256, 0, stream>>>(ss, small, flag);

    // CSR build (shared by both layers)
    hipMemsetAsync(deg, 0, (size_t)N * 4, stream);
    int eb = (E + 255) / 256;
    count_deg<<<eb, 256, 0, stream>>>(dstIdx, deg, E);
    int nchunks = (N + SCAN_CHUNK - 1) / SCAN_CHUNK;
    chunk_sum_kernel<<<nchunks, 256, 0, stream>>>(deg, csums, N);
    scan_phase2<<<N / SCAN_CHUNK + 1, 256, 0, stream>>>(deg, csums, rowptr, cursor, N);
    fill_kernel<<<eb, 256, 0, stream>>>(srcIdx, dstIdx, cursor, csr_src, E);

    int gb = (N + 127) / 128;
    int ab = (N + 3) / 4;

    // layer 0
    gemm_kernel<1, false><<<gb, 256, 0, stream>>>(xb, xb, Wt0, small + 0, msg, N);
    aggregate_kernel<<<ab, 256, 0, stream>>>(msg, rowptr, csr_src, agg, N);
    gemm_kernel<2, true><<<gb, 256, 0, stream>>>(agg, xb, WtA0, small + 128, h0, N);

    // layer 1
    gemm_kernel<1, false><<<gb, 256, 0, stream>>>(h0, h0, Wt1, small + 256, msg, N);
    aggregate_kernel<<<ab, 256, 0, stream>>>(msg, rowptr, csr_src, agg, N);
    gemm_kernel<2, true><<<gb, 256, 0, stream>>>(agg, h0, WtA1, small + 384, h1, N);

    // pool + head
    hipMemsetAsync(pooled, 0, (size_t)G * 128 * 4, stream);
    pool_kernel<<<(N + 127) / 128, 256, 0, stream>>>(h1, batch, pooled, N);
    final_kernel<<<G, 256, 0, stream>>>((const float*)pooled, small, d_out, G, flag);
}

// Round 5
// 282.677 us; speedup vs baseline: 2.0713x; 1.1472x over previous
//
#include <hip/hip_runtime.h>

// ---------- bf16 helpers (raw ushort representation) ----------
__device__ __forceinline__ float bf2f(ushort u) {
    union { uint i; float f; } c; c.i = ((uint)u) << 16; return c.f;
}
__device__ __forceinline__ float bf2lo(uint v) {
    union { uint i; float f; } c; c.i = v << 16; return c.f;
}
__device__ __forceinline__ float bf2hi(uint v) {
    union { uint i; float f; } c; c.i = v & 0xffff0000u; return c.f;
}
__device__ __forceinline__ ushort f2bf(float f) {
    union { float f; uint i; } c; c.f = f;
    uint b = c.i;
    uint r = (b + 0x7fffu + ((b >> 16) & 1u)) >> 16;
    return (ushort)r;
}

typedef __bf16 v8bf __attribute__((ext_vector_type(8)));
typedef float  v4f  __attribute__((ext_vector_type(4)));

// ---------- dtype sniff: are float inputs f32 (flag=1) or bf16 (flag=0)? ----------
__global__ __launch_bounds__(256) void sniff_kernel(const uint* __restrict__ words, int* __restrict__ flag) {
    __shared__ int s[256];
    int t = threadIdx.x;
    int bad = 0;
    for (int i = t; i < 2048; i += 256) {
        uint w = words[i];
        uint exp = (w >> 7) & 0xffu;   // exponent of low u16 as bf16
        if (exp >= 143u) bad++;        // |val| >= 2^16 -> impossible for sane data
    }
    s[t] = bad;
    __syncthreads();
    for (int o = 128; o; o >>= 1) {
        if (t < o) s[t] += s[t + o];
        __syncthreads();
    }
    if (t == 0) *flag = (s[0] > 64) ? 1 : 0;
}

__device__ __forceinline__ ushort load_conv(const void* src, int i, int isf32) {
    return isf32 ? f2bf(((const float*)src)[i]) : ((const ushort*)src)[i];
}

// ---------- convert x to canonical bf16, 8 elems/thread ----------
__global__ __launch_bounds__(256) void convert_x8(const void* __restrict__ src, ushort* __restrict__ dst,
                                                  int n, const int* __restrict__ flag) {
    int idx = blockIdx.x * 256 + threadIdx.x;
    int base = idx * 8;
    if (base + 8 <= n) {
        if (*flag) {
            const float4* s4 = (const float4*)src;
            float4 a = s4[idx * 2], b = s4[idx * 2 + 1];
            union { ushort u[8]; uint4 v; } o;
            o.u[0] = f2bf(a.x); o.u[1] = f2bf(a.y); o.u[2] = f2bf(a.z); o.u[3] = f2bf(a.w);
            o.u[4] = f2bf(b.x); o.u[5] = f2bf(b.y); o.u[6] = f2bf(b.z); o.u[7] = f2bf(b.w);
            *(uint4*)(dst + base) = o.v;
        } else {
            *(uint4*)(dst + base) = ((const uint4*)src)[idx];
        }
    } else {
        int isf = *flag;
        for (int i = base; i < n; i++) dst[i] = load_conv(src, i, isf);
    }
}

// ---------- weight prep: 4 transposes + small params, one kernel ----------
struct SmallSrcs { const void* p[8]; };
// small offsets: lin_b0 0, agg_b0 128, lin_b1 256, agg_b1 384, mp_w1 512, mp_b1 16896, mp_w2 17024, mp_b2 17280 (end 17282)
__global__ __launch_bounds__(256) void prep_weights(
    const void* __restrict__ w0, const void* __restrict__ wa0,
    const void* __restrict__ w1, const void* __restrict__ wa1,
    ushort* __restrict__ t0, ushort* __restrict__ ta0,
    ushort* __restrict__ t1, ushort* __restrict__ ta1,
    SmallSrcs s, ushort* __restrict__ smalldst,
    const int* __restrict__ flag) {
    int idx = blockIdx.x * 256 + threadIdx.x;   // 0 .. 115585
    if (idx < 98304) {
        const void* W; ushort* T; int K; int local;
        if (idx < 16384)      { W = w0;  T = t0;  K = 128; local = idx; }
        else if (idx < 49152) { W = wa0; T = ta0; K = 256; local = idx - 16384; }
        else if (idx < 65536) { W = w1;  T = t1;  K = 128; local = idx - 49152; }
        else                  { W = wa1; T = ta1; K = 256; local = idx - 65536; }
        ushort v = load_conv(W, local, *flag);
        int k = local >> 7;       // row in W
        int n = local & 127;      // col in W
        T[(size_t)n * K + k] = v;
    } else {
        int si = idx - 98304;
        if (si >= 17282) return;
        const int offs[9] = {0, 128, 256, 384, 512, 16896, 17024, 17280, 17282};
        int seg = 0;
        while (si >= offs[seg + 1]) seg++;
        smalldst[si] = load_conv(s.p[seg], si - offs[seg], *flag);
    }
}

// ---------- CSR build ----------
__global__ __launch_bounds__(256) void count_deg(const int* __restrict__ dst, int* __restrict__ deg, int E) {
    int i = blockIdx.x * 256 + threadIdx.x;
    if (i < E) atomicAdd(&deg[dst[i]], 1);
}

#define SCAN_CHUNK 1024

__global__ __launch_bounds__(256) void chunk_sum_kernel(const int* __restrict__ deg,
                                                        int* __restrict__ csums, int n) {
    __shared__ int s[256];
    int t = threadIdx.x;
    int base = blockIdx.x * SCAN_CHUNK + t * 4;
    int v = 0;
    if (base + 4 <= n) {
        int4 q = *(const int4*)(deg + base);
        v = q.x + q.y + q.z + q.w;
    } else {
        for (int i = base; i < n; i++) v += deg[i];
    }
    s[t] = v;
    __syncthreads();
    for (int o = 128; o; o >>= 1) {
        if (t < o) s[t] += s[t + o];
        __syncthreads();
    }
    if (t == 0) csums[blockIdx.x] = s[0];
}

__global__ __launch_bounds__(256) void scan_phase2(const int* __restrict__ deg,
                                                   const int* __restrict__ csums,
                                                   int* __restrict__ rowptr, int* __restrict__ cursor,
                                                   int n) {
    __shared__ int red[256];
    int t = threadIdx.x, b = blockIdx.x;
    int v = 0;
    for (int i = t; i < b; i += 256) v += csums[i];
    red[t] = v;
    __syncthreads();
    for (int o = 128; o; o >>= 1) {
        if (t < o) red[t] += red[t + o];
        __syncthreads();
    }
    int chunkOff = red[0];
    __syncthreads();
    int base = b * SCAN_CHUNK + t * 4;
    int d0 = 0, d1 = 0, d2 = 0, d3 = 0;
    if (base + 4 <= n) {
        int4 q = *(const int4*)(deg + base);
        d0 = q.x; d1 = q.y; d2 = q.z; d3 = q.w;
    } else {
        if (base < n)     d0 = deg[base];
        if (base + 1 < n) d1 = deg[base + 1];
        if (base + 2 < n) d2 = deg[base + 2];
        if (base + 3 < n) d3 = deg[base + 3];
    }
    int s4 = d0 + d1 + d2 + d3;
    red[t] = s4;
    __syncthreads();
    for (int o = 1; o < 256; o <<= 1) {
        int u = (t >= o) ? red[t - o] : 0;
        __syncthreads();
        red[t] += u;
        __syncthreads();
    }
    int run = chunkOff + red[t] - s4;  // exclusive prefix at base
    if (base < n)     { rowptr[base]     = run; cursor[base]     = run; run += d0; }
    if (base + 1 < n) { rowptr[base + 1] = run; cursor[base + 1] = run; run += d1; }
    if (base + 2 < n) { rowptr[base + 2] = run; cursor[base + 2] = run; run += d2; }
    if (base + 3 < n) { rowptr[base + 3] = run; cursor[base + 3] = run; run += d3; }
    if (n >= base && n < base + 4) rowptr[n] = run;  // exactly one thread grid-wide
}

__global__ __launch_bounds__(256) void fill_kernel(const int* __restrict__ src, const int* __restrict__ dst,
                                                   int* __restrict__ cursor, int* __restrict__ csr_src, int E) {
    int i = blockIdx.x * 256 + threadIdx.x;
    if (i < E) {
        int pos = atomicAdd(&cursor[dst[i]], 1);
        csr_src[pos] = src[i];
    }
}

// ---------- MFMA GEMM: relu(A @ Bt^T + bias), optional row-L2-normalize, optional fused max-pool ----------
template <int NSTAGE, bool NORM, bool POOL>
__global__ __launch_bounds__(256) void gemm_kernel(
    const ushort* __restrict__ A0, const ushort* __restrict__ A1,
    const ushort* __restrict__ Bt, const ushort* __restrict__ bias,
    ushort* __restrict__ Cout, int M,
    const int* __restrict__ batchv, int* __restrict__ pooled) {
    __shared__ __bf16 As[128 * 72];  // 64 k-chunk, stride 72 (pad 8)
    __shared__ __bf16 Bs[128 * 72];
    __shared__ int PoolLoc[POOL ? 8 * 128 : 1];
    const int t = threadIdx.x;
    const int w = t >> 6, lane = t & 63, ln = lane & 15, q = lane >> 4;
    const int blockRow = blockIdx.x * 128;
    const int K = NSTAGE * 128;

    if (POOL) {
        for (int i = t; i < 8 * 128; i += 256) PoolLoc[i] = 0;
    }

    v4f acc[2][8];
#pragma unroll
    for (int i = 0; i < 2; i++)
#pragma unroll
        for (int j = 0; j < 8; j++) acc[i][j] = (v4f){0.f, 0.f, 0.f, 0.f};

    for (int kc = 0; kc < K; kc += 64) {
        const ushort* Ap = (kc < 128) ? A0 : A1;
        int kin = kc & 127;
#pragma unroll
        for (int i = 0; i < 4; i++) {
            int c = i * 256 + t;
            int row = c >> 3, c8 = c & 7;
            int grow = blockRow + row; if (grow >= M) grow = M - 1;
            *(uint4*)&As[row * 72 + c8 * 8] = *(const uint4*)(Ap + (size_t)grow * 128 + kin + c8 * 8);
            *(uint4*)&Bs[row * 72 + c8 * 8] = *(const uint4*)(Bt + (size_t)row * K + kc + c8 * 8);
        }
        __syncthreads();
#pragma unroll
        for (int k0 = 0; k0 < 64; k0 += 32) {
            v8bf a0 = *(const v8bf*)&As[(w * 32 + ln) * 72 + k0 + q * 8];
            v8bf a1 = *(const v8bf*)&As[(w * 32 + 16 + ln) * 72 + k0 + q * 8];
#pragma unroll
            for (int nt = 0; nt < 8; nt++) {
                v8bf b = *(const v8bf*)&Bs[(nt * 16 + ln) * 72 + k0 + q * 8];
                acc[0][nt] = __builtin_amdgcn_mfma_f32_16x16x32_bf16(a0, b, acc[0][nt], 0, 0, 0);
                acc[1][nt] = __builtin_amdgcn_mfma_f32_16x16x32_bf16(a1, b, acc[1][nt], 0, 0, 0);
            }
        }
        __syncthreads();
    }

    float biasf[8];
#pragma unroll
    for (int nt = 0; nt < 8; nt++) biasf[nt] = bf2f(bias[nt * 16 + ln]);

    const int minB = POOL ? batchv[blockRow < M ? blockRow : M - 1] : 0;

#pragma unroll
    for (int mt = 0; mt < 2; mt++) {
        float v[8][4];
#pragma unroll
        for (int nt = 0; nt < 8; nt++)
#pragma unroll
            for (int r = 0; r < 4; r++) {
                float x = acc[mt][nt][r] + biasf[nt];
                v[nt][r] = x > 0.f ? x : 0.f;
            }
        float inv[4];
        if (NORM) {
#pragma unroll
            for (int r = 0; r < 4; r++) {
                float p = 0.f;
#pragma unroll
                for (int nt = 0; nt < 8; nt++) p += v[nt][r] * v[nt][r];
                p += __shfl_xor(p, 1);
                p += __shfl_xor(p, 2);
                p += __shfl_xor(p, 4);
                p += __shfl_xor(p, 8);
                inv[r] = 1.0f / fmaxf(sqrtf(p), 1e-12f);
            }
        }
        int rowbase = blockRow + w * 32 + mt * 16 + q * 4;
#pragma unroll
        for (int r = 0; r < 4; r++) {
            int grow = rowbase + r;
            if (grow < M) {
                if (POOL) {
                    int b = batchv[grow];
                    int rel = b - minB;
#pragma unroll
                    for (int nt = 0; nt < 8; nt++) {
                        float x = v[nt][r] * inv[r];
                        int xi = __float_as_int(x);
                        if (rel < 8) atomicMax(&PoolLoc[rel * 128 + nt * 16 + ln], xi);
                        else         atomicMax(&pooled[b * 128 + nt * 16 + ln], xi);
                    }
                } else {
#pragma unroll
                    for (int nt = 0; nt < 8; nt++) {
                        float x = NORM ? v[nt][r] * inv[r] : v[nt][r];
                        Cout[(size_t)grow * 128 + nt * 16 + ln] = f2bf(x);
                    }
                }
            }
        }
    }

    if (POOL) {
        __syncthreads();
        int lastRow = blockRow + 127; if (lastRow >= M) lastRow = M - 1;
        int span = batchv[lastRow] - minB + 1;
        if (span > 8) span = 8;
        for (int i = t; i < span * 128; i += 256) {
            int vv = PoolLoc[i];
            if (vv != 0) atomicMax(&pooled[(minB + (i >> 7)) * 128 + (i & 127)], vv);
        }
    }
}

// ---------- CSR mean-aggregate: 4 edges in flight per wave, 16B/lane ----------
__global__ __launch_bounds__(256) void aggregate_kernel(
    const ushort* __restrict__ msg, const int* __restrict__ rowptr,
    const int* __restrict__ csr_src, ushort* __restrict__ agg, int n) {
    int wid = (int)((blockIdx.x * 256u + threadIdx.x) >> 6);
    int lane = threadIdx.x & 63;
    int sub = lane >> 4;       // which of 4 concurrent edges
    int l16 = lane & 15;       // 16 lanes x 8 bf16 (16B) cover a 256B row
    if (wid >= n) return;
    int start = rowptr[wid], end = rowptr[wid + 1];
    float a[8] = {0.f, 0.f, 0.f, 0.f, 0.f, 0.f, 0.f, 0.f};
#pragma unroll 2
    for (int j = start + sub; j < end; j += 4) {
        int s = csr_src[j];
        uint4 v = *(const uint4*)(msg + (size_t)s * 128 + l16 * 8);
        a[0] += bf2lo(v.x); a[1] += bf2hi(v.x);
        a[2] += bf2lo(v.y); a[3] += bf2hi(v.y);
        a[4] += bf2lo(v.z); a[5] += bf2hi(v.z);
        a[6] += bf2lo(v.w); a[7] += bf2hi(v.w);
    }
#pragma unroll
    for (int i = 0; i < 8; i++) {
        a[i] += __shfl_xor(a[i], 16);
        a[i] += __shfl_xor(a[i], 32);
    }
    if (sub == 0) {
        float inv = 1.0f / fmaxf((float)(end - start), 1.0f);
        union { ushort u[8]; uint4 v; } o;
#pragma unroll
        for (int i = 0; i < 8; i++) o.u[i] = f2bf(a[i] * inv);
        *(uint4*)(agg + (size_t)wid * 128 + l16 * 8) = o.v;
    }
}

// ---------- MLP head + log_softmax: one block per graph ----------
__global__ __launch_bounds__(256) void final_kernel(const float* __restrict__ pooled,
                                                    const ushort* __restrict__ small,
                                                    void* __restrict__ out, int G,
                                                    const int* __restrict__ flag) {
    __shared__ float P[128];
    __shared__ float Thalf[128];
    __shared__ float T[128];
    __shared__ float R0[128], R1[128];
    const ushort* w1 = small + 512;
    const ushort* b1 = small + 16896;
    const ushort* w2 = small + 17024;
    const ushort* b2 = small + 17280;
    int g = blockIdx.x;
    int t = threadIdx.x;
    int j = t & 127, half = t >> 7;
    if (t < 128) P[t] = pooled[g * 128 + t];
    __syncthreads();
    float acc = 0.f;
    int k0 = half * 64;
#pragma unroll 8
    for (int k = k0; k < k0 + 64; k++) acc += P[k] * bf2f(w1[k * 128 + j]);
    if (half == 0) Thalf[j] = acc;
    __syncthreads();
    if (half == 1) T[j] = Thalf[j] + acc + bf2f(b1[j]);
    __syncthreads();
    if (t < 128) {
        float tv = T[t];
        R0[t] = tv * bf2f(w2[t * 2]);
        R1[t] = tv * bf2f(w2[t * 2 + 1]);
    }
    __syncthreads();
    for (int o = 64; o; o >>= 1) {
        if (t < o) { R0[t] += R0[t + o]; R1[t] += R1[t + o]; }
        __syncthreads();
    }
    if (t == 0) {
        float z0 = R0[0] + bf2f(b2[0]);
        float z1 = R1[0] + bf2f(b2[1]);
        float m = fmaxf(z0, z1);
        float l = m + logf(expf(z0 - m) + expf(z1 - m));
        float o0 = z0 - l, o1 = z1 - l;
        if (*flag) {
            ((float*)out)[2 * g]     = o0;
            ((float*)out)[2 * g + 1] = o1;
        } else {
            ((ushort*)out)[2 * g]     = f2bf(o0);
            ((ushort*)out)[2 * g + 1] = f2bf(o1);
        }
    }
}

extern "C" void kernel_launch(void* const* d_in, const int* in_sizes, int n_in,
                              void* d_out, int out_size, void* d_ws, size_t ws_size,
                              hipStream_t stream) {
    const void* x      = d_in[0];
    const int*  ei     = (const int*)d_in[1];
    const int*  batch  = (const int*)d_in[2];

    const int N = in_sizes[0] / 128;   // 50000 nodes
    const int E = in_sizes[1] / 2;     // 600000 edges
    const int G = out_size / 2;        // 64 graphs
    const int* srcIdx = ei;
    const int* dstIdx = ei + E;

    char* ws = (char*)d_ws;
    size_t off = 0;
    auto alloc = [&](size_t bytes) -> void* {
        off = (off + 255) & ~(size_t)255;
        void* p = ws + off;
        off += bytes;
        return p;
    };
    int*    flag    = (int*)alloc(4);
    int*    deg     = (int*)alloc((size_t)N * 4);
    int*    rowptr  = (int*)alloc((size_t)(N + 1) * 4);
    int*    cursor  = (int*)alloc((size_t)N * 4);
    int*    csr_src = (int*)alloc((size_t)E * 4);
    int*    csums   = (int*)alloc(((size_t)N / SCAN_CHUNK + 2) * 4);
    ushort* Wt0     = (ushort*)alloc(128 * 128 * 2);
    ushort* WtA0    = (ushort*)alloc(256 * 128 * 2);
    ushort* Wt1     = (ushort*)alloc(128 * 128 * 2);
    ushort* WtA1    = (ushort*)alloc(256 * 128 * 2);
    ushort* small   = (ushort*)alloc(17282 * 2);
    ushort* xb      = (ushort*)alloc((size_t)N * 128 * 2);
    ushort* msg     = (ushort*)alloc((size_t)N * 128 * 2);
    ushort* agg     = (ushort*)alloc((size_t)N * 128 * 2);
    ushort* h0      = (ushort*)alloc((size_t)N * 128 * 2);
    int*    pooled  = (int*)alloc((size_t)G * 128 * 4);

    // dtype sniff + canonicalize everything to bf16
    sniff_kernel<<<1, 256, 0, stream>>>((const uint*)x, flag);
    convert_x8<<<(N * 128 + 2047) / 2048, 256, 0, stream>>>(x, xb, N * 128, flag);
    SmallSrcs ss;
    ss.p[0] = d_in[4];  ss.p[1] = d_in[6];  ss.p[2] = d_in[8];  ss.p[3] = d_in[10];
    ss.p[4] = d_in[11]; ss.p[5] = d_in[12]; ss.p[6] = d_in[13]; ss.p[7] = d_in[14];
    prep_weights<<<452, 256, 0, stream>>>(d_in[3], d_in[5], d_in[7], d_in[9],
                                          Wt0, WtA0, Wt1, WtA1, ss, small, flag);

    // CSR build (shared by both layers)
    hipMemsetAsync(deg, 0, (size_t)N * 4, stream);
    hipMemsetAsync(pooled, 0, (size_t)G * 128 * 4, stream);
    int eb = (E + 255) / 256;
    count_deg<<<eb, 256, 0, stream>>>(dstIdx, deg, E);
    int nchunks = (N + SCAN_CHUNK - 1) / SCAN_CHUNK;
    chunk_sum_kernel<<<nchunks, 256, 0, stream>>>(deg, csums, N);
    scan_phase2<<<N / SCAN_CHUNK + 1, 256, 0, stream>>>(deg, csums, rowptr, cursor, N);
    fill_kernel<<<eb, 256, 0, stream>>>(srcIdx, dstIdx, cursor, csr_src, E);

    int gb = (N + 127) / 128;
    int ab = (N + 3) / 4;

    // layer 0
    gemm_kernel<1, false, false><<<gb, 256, 0, stream>>>(xb, xb, Wt0, small + 0, msg, N, nullptr, nullptr);
    aggregate_kernel<<<ab, 256, 0, stream>>>(msg, rowptr, csr_src, agg, N);
    gemm_kernel<2, true, false><<<gb, 256, 0, stream>>>(agg, xb, WtA0, small + 128, h0, N, nullptr, nullptr);

    // layer 1
    gemm_kernel<1, false, false><<<gb, 256, 0, stream>>>(h0, h0, Wt1, small + 256, msg, N, nullptr, nullptr);
    aggregate_kernel<<<ab, 256, 0, stream>>>(msg, rowptr, csr_src, agg, N);
    // layer-1 update GEMM with fused max-pool (h1 never materialized)
    gemm_kernel<2, true, true><<<gb, 256, 0, stream>>>(agg, h0, WtA1, small + 384, nullptr, N, batch, pooled);

    // head
    final_kernel<<<G, 256, 0, stream>>>((const float*)pooled, small, d_out, G, flag);
}

// Round 6
// 273.456 us; speedup vs baseline: 2.1411x; 1.0337x over previous
//
#include <hip/hip_runtime.h>

// ---------- bf16 helpers (raw ushort representation) ----------
__device__ __forceinline__ float bf2f(ushort u) {
    union { uint i; float f; } c; c.i = ((uint)u) << 16; return c.f;
}
__device__ __forceinline__ float bf2lo(uint v) {
    union { uint i; float f; } c; c.i = v << 16; return c.f;
}
__device__ __forceinline__ float bf2hi(uint v) {
    union { uint i; float f; } c; c.i = v & 0xffff0000u; return c.f;
}
__device__ __forceinline__ ushort f2bf(float f) {
    union { float f; uint i; } c; c.f = f;
    uint b = c.i;
    uint r = (b + 0x7fffu + ((b >> 16) & 1u)) >> 16;
    return (ushort)r;
}

typedef __bf16 v8bf __attribute__((ext_vector_type(8)));
typedef float  v4f  __attribute__((ext_vector_type(4)));

// ---------- dtype sniff: are float inputs f32 (flag=1) or bf16 (flag=0)? ----------
__global__ __launch_bounds__(256) void sniff_kernel(const uint* __restrict__ words, int* __restrict__ flag) {
    __shared__ int s[256];
    int t = threadIdx.x;
    int bad = 0;
    for (int i = t; i < 2048; i += 256) {
        uint w = words[i];
        uint exp = (w >> 7) & 0xffu;   // exponent of low u16 as bf16
        if (exp >= 143u) bad++;        // |val| >= 2^16 -> impossible for sane data
    }
    s[t] = bad;
    __syncthreads();
    for (int o = 128; o; o >>= 1) {
        if (t < o) s[t] += s[t + o];
        __syncthreads();
    }
    if (t == 0) *flag = (s[0] > 64) ? 1 : 0;
}

__device__ __forceinline__ ushort load_conv(const void* src, int i, int isf32) {
    return isf32 ? f2bf(((const float*)src)[i]) : ((const ushort*)src)[i];
}

// ---------- phase A: convert x (bf16 canonical) + weight prep + zero deg/pooled ----------
struct SmallSrcs { const void* p[8]; };
// small offsets: lin_b0 0, agg_b0 128, lin_b1 256, agg_b1 384, mp_w1 512, mp_b1 16896, mp_w2 17024, mp_b2 17280 (end 17282)
__global__ __launch_bounds__(256) void phaseA(
    const void* __restrict__ x, ushort* __restrict__ xb, int nx, int nbconv,
    const void* __restrict__ w0, const void* __restrict__ wa0,
    const void* __restrict__ w1, const void* __restrict__ wa1,
    ushort* __restrict__ t0, ushort* __restrict__ ta0,
    ushort* __restrict__ t1, ushort* __restrict__ ta1,
    SmallSrcs s, ushort* __restrict__ smalldst,
    int* __restrict__ deg, int* __restrict__ pooled, int N, int G,
    const int* __restrict__ flag) {
    int b = blockIdx.x, t = threadIdx.x;
    if (b < nbconv) {
        // convert x: 8 elems/thread
        int idx = b * 256 + t;
        int base = idx * 8;
        if (base + 8 <= nx) {
            if (*flag) {
                const float4* s4 = (const float4*)x;
                float4 a = s4[idx * 2], bb = s4[idx * 2 + 1];
                union { ushort u[8]; uint4 v; } o;
                o.u[0] = f2bf(a.x); o.u[1] = f2bf(a.y); o.u[2] = f2bf(a.z); o.u[3] = f2bf(a.w);
                o.u[4] = f2bf(bb.x); o.u[5] = f2bf(bb.y); o.u[6] = f2bf(bb.z); o.u[7] = f2bf(bb.w);
                *(uint4*)(xb + base) = o.v;
            } else {
                *(uint4*)(xb + base) = ((const uint4*)x)[idx];
            }
        } else {
            int isf = *flag;
            for (int i = base; i < nx; i++) xb[i] = load_conv(x, i, isf);
        }
    } else if (b < nbconv + 452) {
        int idx = (b - nbconv) * 256 + t;   // 0 .. 115585
        if (idx < 98304) {
            const void* W; ushort* T; int K; int local;
            if (idx < 16384)      { W = w0;  T = t0;  K = 128; local = idx; }
            else if (idx < 49152) { W = wa0; T = ta0; K = 256; local = idx - 16384; }
            else if (idx < 65536) { W = w1;  T = t1;  K = 128; local = idx - 49152; }
            else                  { W = wa1; T = ta1; K = 256; local = idx - 65536; }
            ushort v = load_conv(W, local, *flag);
            int k = local >> 7;       // row in W
            int n = local & 127;      // col in W
            T[(size_t)n * K + k] = v;
        } else {
            int si = idx - 98304;
            if (si < 17282) {
                const int offs[9] = {0, 128, 256, 384, 512, 16896, 17024, 17280, 17282};
                int seg = 0;
                while (si >= offs[seg + 1]) seg++;
                smalldst[si] = load_conv(s.p[seg], si - offs[seg], *flag);
            }
        }
    } else {
        // zero deg (N ints) + pooled (G*128 ints), int4-vectorized
        int idx = (b - nbconv - 452) * 256 + t;
        int nd4 = N >> 2;
        int4 z = {0, 0, 0, 0};
        if (idx < nd4) ((int4*)deg)[idx] = z;
        else if (idx == nd4) { for (int i = nd4 * 4; i < N; i++) deg[i] = 0; }
        else if (idx - nd4 - 1 < G * 32) ((int4*)pooled)[idx - nd4 - 1] = z;
    }
}

// ---------- CSR build ----------
__global__ __launch_bounds__(256) void count_deg(const int* __restrict__ dst, int* __restrict__ deg, int E) {
    int i = blockIdx.x * 256 + threadIdx.x;
    if (i < E) atomicAdd(&deg[dst[i]], 1);
}

#define SCAN_CHUNK 1024

__global__ __launch_bounds__(256) void chunk_sum_kernel(const int* __restrict__ deg,
                                                        int* __restrict__ csums, int n) {
    __shared__ int s[256];
    int t = threadIdx.x;
    int base = blockIdx.x * SCAN_CHUNK + t * 4;
    int v = 0;
    if (base + 4 <= n) {
        int4 q = *(const int4*)(deg + base);
        v = q.x + q.y + q.z + q.w;
    } else {
        for (int i = base; i < n; i++) v += deg[i];
    }
    s[t] = v;
    __syncthreads();
    for (int o = 128; o; o >>= 1) {
        if (t < o) s[t] += s[t + o];
        __syncthreads();
    }
    if (t == 0) csums[blockIdx.x] = s[0];
}

__global__ __launch_bounds__(256) void scan_phase2(const int* __restrict__ deg,
                                                   const int* __restrict__ csums,
                                                   int* __restrict__ rowptr, int* __restrict__ cursor,
                                                   int n) {
    __shared__ int red[256];
    int t = threadIdx.x, b = blockIdx.x;
    int v = 0;
    for (int i = t; i < b; i += 256) v += csums[i];
    red[t] = v;
    __syncthreads();
    for (int o = 128; o; o >>= 1) {
        if (t < o) red[t] += red[t + o];
        __syncthreads();
    }
    int chunkOff = red[0];
    __syncthreads();
    int base = b * SCAN_CHUNK + t * 4;
    int d0 = 0, d1 = 0, d2 = 0, d3 = 0;
    if (base + 4 <= n) {
        int4 q = *(const int4*)(deg + base);
        d0 = q.x; d1 = q.y; d2 = q.z; d3 = q.w;
    } else {
        if (base < n)     d0 = deg[base];
        if (base + 1 < n) d1 = deg[base + 1];
        if (base + 2 < n) d2 = deg[base + 2];
        if (base + 3 < n) d3 = deg[base + 3];
    }
    int s4 = d0 + d1 + d2 + d3;
    red[t] = s4;
    __syncthreads();
    for (int o = 1; o < 256; o <<= 1) {
        int u = (t >= o) ? red[t - o] : 0;
        __syncthreads();
        red[t] += u;
        __syncthreads();
    }
    int run = chunkOff + red[t] - s4;  // exclusive prefix at base
    if (base < n)     { rowptr[base]     = run; cursor[base]     = run; run += d0; }
    if (base + 1 < n) { rowptr[base + 1] = run; cursor[base + 1] = run; run += d1; }
    if (base + 2 < n) { rowptr[base + 2] = run; cursor[base + 2] = run; run += d2; }
    if (base + 3 < n) { rowptr[base + 3] = run; cursor[base + 3] = run; run += d3; }
    if (n >= base && n < base + 4) rowptr[n] = run;  // exactly one thread grid-wide
}

__global__ __launch_bounds__(256) void fill_kernel(const int* __restrict__ src, const int* __restrict__ dst,
                                                   int* __restrict__ cursor, int* __restrict__ csr_src, int E) {
    int i = blockIdx.x * 256 + threadIdx.x;
    if (i < E) {
        int pos = atomicAdd(&cursor[dst[i]], 1);
        csr_src[pos] = src[i];
    }
}

// ---------- MFMA GEMM ----------
// Phase 1: C = relu(A @ Bt^T + bias) [+ row-L2-normalize if NORM]
//   POOL: fused segment-max into pooled (no C store)
//   FUSE: after phase 1, compute Mout = relu(H @ Bt2^T + bias2) with H from LDS
template <int NSTAGE, bool NORM, bool POOL, bool FUSE>
__global__ __launch_bounds__(256) void gemm_kernel(
    const ushort* __restrict__ A0, const ushort* __restrict__ A1,
    const ushort* __restrict__ Bt, const ushort* __restrict__ bias,
    ushort* __restrict__ Cout, int M,
    const int* __restrict__ batchv, int* __restrict__ pooled,
    const ushort* __restrict__ Bt2, const ushort* __restrict__ bias2,
    ushort* __restrict__ Mout) {
    // LDS layout: phase1 As at [0], Bs at [9216]. FUSE phase2: Hs at [0] (128x136), Bs2 at [17408]
    constexpr int LDSN = FUSE ? (128 * 136 + 128 * 72) : (2 * 128 * 72);
    __shared__ __bf16 lds[LDSN];
    __shared__ int PoolLoc[POOL ? 8 * 128 : 1];
    __bf16* As = lds;
    __bf16* Bs = lds + 128 * 72;
    const int t = threadIdx.x;
    const int w = t >> 6, lane = t & 63, ln = lane & 15, q = lane >> 4;
    const int blockRow = blockIdx.x * 128;
    const int K = NSTAGE * 128;

    if (POOL) {
        for (int i = t; i < 8 * 128; i += 256) PoolLoc[i] = 0;
    }

    v4f acc[2][8];
#pragma unroll
    for (int i = 0; i < 2; i++)
#pragma unroll
        for (int j = 0; j < 8; j++) acc[i][j] = (v4f){0.f, 0.f, 0.f, 0.f};

    for (int kc = 0; kc < K; kc += 64) {
        const ushort* Ap = (kc < 128) ? A0 : A1;
        int kin = kc & 127;
#pragma unroll
        for (int i = 0; i < 4; i++) {
            int c = i * 256 + t;
            int row = c >> 3, c8 = c & 7;
            int grow = blockRow + row; if (grow >= M) grow = M - 1;
            *(uint4*)&As[row * 72 + c8 * 8] = *(const uint4*)(Ap + (size_t)grow * 128 + kin + c8 * 8);
            *(uint4*)&Bs[row * 72 + c8 * 8] = *(const uint4*)(Bt + (size_t)row * K + kc + c8 * 8);
        }
        __syncthreads();
#pragma unroll
        for (int k0 = 0; k0 < 64; k0 += 32) {
            v8bf a0 = *(const v8bf*)&As[(w * 32 + ln) * 72 + k0 + q * 8];
            v8bf a1 = *(const v8bf*)&As[(w * 32 + 16 + ln) * 72 + k0 + q * 8];
#pragma unroll
            for (int nt = 0; nt < 8; nt++) {
                v8bf b = *(const v8bf*)&Bs[(nt * 16 + ln) * 72 + k0 + q * 8];
                acc[0][nt] = __builtin_amdgcn_mfma_f32_16x16x32_bf16(a0, b, acc[0][nt], 0, 0, 0);
                acc[1][nt] = __builtin_amdgcn_mfma_f32_16x16x32_bf16(a1, b, acc[1][nt], 0, 0, 0);
            }
        }
        __syncthreads();
    }

    float biasf[8];
#pragma unroll
    for (int nt = 0; nt < 8; nt++) biasf[nt] = bf2f(bias[nt * 16 + ln]);

    const int minB = POOL ? batchv[blockRow < M ? blockRow : M - 1] : 0;
    __bf16* Hs = lds;                       // FUSE phase-2 A tile (128 x 136)
    ushort* HsU = (ushort*)Hs;

#pragma unroll
    for (int mt = 0; mt < 2; mt++) {
        float v[8][4];
#pragma unroll
        for (int nt = 0; nt < 8; nt++)
#pragma unroll
            for (int r = 0; r < 4; r++) {
                float x = acc[mt][nt][r] + biasf[nt];
                v[nt][r] = x > 0.f ? x : 0.f;
            }
        float inv[4];
        if (NORM) {
#pragma unroll
            for (int r = 0; r < 4; r++) {
                float p = 0.f;
#pragma unroll
                for (int nt = 0; nt < 8; nt++) p += v[nt][r] * v[nt][r];
                p += __shfl_xor(p, 1);
                p += __shfl_xor(p, 2);
                p += __shfl_xor(p, 4);
                p += __shfl_xor(p, 8);
                inv[r] = 1.0f / fmaxf(sqrtf(p), 1e-12f);
            }
        }
        int rowloc = w * 32 + mt * 16 + q * 4;
#pragma unroll
        for (int r = 0; r < 4; r++) {
            int grow = blockRow + rowloc + r;
            if (POOL) {
                if (grow < M) {
                    int b = batchv[grow];
                    int rel = b - minB;
#pragma unroll
                    for (int nt = 0; nt < 8; nt++) {
                        float x = v[nt][r] * inv[r];
                        int xi = __float_as_int(x);
                        if (rel < 8) atomicMax(&PoolLoc[rel * 128 + nt * 16 + ln], xi);
                        else         atomicMax(&pooled[b * 128 + nt * 16 + ln], xi);
                    }
                }
            } else {
#pragma unroll
                for (int nt = 0; nt < 8; nt++) {
                    float x = NORM ? v[nt][r] * inv[r] : v[nt][r];
                    ushort xb = f2bf(x);
                    if (grow < M) Cout[(size_t)grow * 128 + nt * 16 + ln] = xb;
                    if (FUSE) HsU[(rowloc + r) * 136 + nt * 16 + ln] = xb;
                }
            }
        }
    }

    if (POOL) {
        __syncthreads();
        int lastRow = blockRow + 127; if (lastRow >= M) lastRow = M - 1;
        int span = batchv[lastRow] - minB + 1;
        if (span > 8) span = 8;
        for (int i = t; i < span * 128; i += 256) {
            int vv = PoolLoc[i];
            if (vv != 0) atomicMax(&pooled[(minB + (i >> 7)) * 128 + (i & 127)], vv);
        }
    }

    if (FUSE) {
        // phase 2: Mout = relu(H @ Bt2^T + bias2), H in LDS (full K=128), Bt2 staged per 64-chunk
        __bf16* Bs2 = lds + 128 * 136;
        v4f acc2[2][8];
#pragma unroll
        for (int i = 0; i < 2; i++)
#pragma unroll
            for (int j = 0; j < 8; j++) acc2[i][j] = (v4f){0.f, 0.f, 0.f, 0.f};

        for (int kc = 0; kc < 128; kc += 64) {
#pragma unroll
            for (int i = 0; i < 4; i++) {
                int c = i * 256 + t;
                int row = c >> 3, c8 = c & 7;
                *(uint4*)&Bs2[row * 72 + c8 * 8] = *(const uint4*)(Bt2 + (size_t)row * 128 + kc + c8 * 8);
            }
            __syncthreads();
#pragma unroll
            for (int k0 = 0; k0 < 64; k0 += 32) {
                v8bf a0 = *(const v8bf*)&Hs[(w * 32 + ln) * 136 + kc + k0 + q * 8];
                v8bf a1 = *(const v8bf*)&Hs[(w * 32 + 16 + ln) * 136 + kc + k0 + q * 8];
#pragma unroll
                for (int nt = 0; nt < 8; nt++) {
                    v8bf b = *(const v8bf*)&Bs2[(nt * 16 + ln) * 72 + k0 + q * 8];
                    acc2[0][nt] = __builtin_amdgcn_mfma_f32_16x16x32_bf16(a0, b, acc2[0][nt], 0, 0, 0);
                    acc2[1][nt] = __builtin_amdgcn_mfma_f32_16x16x32_bf16(a1, b, acc2[1][nt], 0, 0, 0);
                }
            }
            __syncthreads();
        }

        float biasf2[8];
#pragma unroll
        for (int nt = 0; nt < 8; nt++) biasf2[nt] = bf2f(bias2[nt * 16 + ln]);
#pragma unroll
        for (int mt = 0; mt < 2; mt++) {
            int rowbase = blockRow + w * 32 + mt * 16 + q * 4;
#pragma unroll
            for (int r = 0; r < 4; r++) {
                int grow = rowbase + r;
                if (grow < M) {
#pragma unroll
                    for (int nt = 0; nt < 8; nt++) {
                        float x = acc2[mt][nt][r] + biasf2[nt];
                        Mout[(size_t)grow * 128 + nt * 16 + ln] = f2bf(x > 0.f ? x : 0.f);
                    }
                }
            }
        }
    }
}

// ---------- CSR mean-aggregate: 4 edges in flight per wave, 16B/lane ----------
__global__ __launch_bounds__(256) void aggregate_kernel(
    const ushort* __restrict__ msg, const int* __restrict__ rowptr,
    const int* __restrict__ csr_src, ushort* __restrict__ agg, int n) {
    int wid = (int)((blockIdx.x * 256u + threadIdx.x) >> 6);
    int lane = threadIdx.x & 63;
    int sub = lane >> 4;       // which of 4 concurrent edges
    int l16 = lane & 15;       // 16 lanes x 8 bf16 (16B) cover a 256B row
    if (wid >= n) return;
    int start = rowptr[wid], end = rowptr[wid + 1];
    float a[8] = {0.f, 0.f, 0.f, 0.f, 0.f, 0.f, 0.f, 0.f};
#pragma unroll 2
    for (int j = start + sub; j < end; j += 4) {
        int s = csr_src[j];
        uint4 v = *(const uint4*)(msg + (size_t)s * 128 + l16 * 8);
        a[0] += bf2lo(v.x); a[1] += bf2hi(v.x);
        a[2] += bf2lo(v.y); a[3] += bf2hi(v.y);
        a[4] += bf2lo(v.z); a[5] += bf2hi(v.z);
        a[6] += bf2lo(v.w); a[7] += bf2hi(v.w);
    }
#pragma unroll
    for (int i = 0; i < 8; i++) {
        a[i] += __shfl_xor(a[i], 16);
        a[i] += __shfl_xor(a[i], 32);
    }
    if (sub == 0) {
        float inv = 1.0f / fmaxf((float)(end - start), 1.0f);
        union { ushort u[8]; uint4 v; } o;
#pragma unroll
        for (int i = 0; i < 8; i++) o.u[i] = f2bf(a[i] * inv);
        *(uint4*)(agg + (size_t)wid * 128 + l16 * 8) = o.v;
    }
}

// ---------- MLP head + log_softmax: one block per graph ----------
__global__ __launch_bounds__(256) void final_kernel(const float* __restrict__ pooled,
                                                    const ushort* __restrict__ small,
                                                    void* __restrict__ out, int G,
                                                    const int* __restrict__ flag) {
    __shared__ float P[128];
    __shared__ float Thalf[128];
    __shared__ float T[128];
    __shared__ float R0[128], R1[128];
    const ushort* w1 = small + 512;
    const ushort* b1 = small + 16896;
    const ushort* w2 = small + 17024;
    const ushort* b2 = small + 17280;
    int g = blockIdx.x;
    int t = threadIdx.x;
    int j = t & 127, half = t >> 7;
    if (t < 128) P[t] = pooled[g * 128 + t];
    __syncthreads();
    float acc = 0.f;
    int k0 = half * 64;
#pragma unroll 8
    for (int k = k0; k < k0 + 64; k++) acc += P[k] * bf2f(w1[k * 128 + j]);
    if (half == 0) Thalf[j] = acc;
    __syncthreads();
    if (half == 1) T[j] = Thalf[j] + acc + bf2f(b1[j]);
    __syncthreads();
    if (t < 128) {
        float tv = T[t];
        R0[t] = tv * bf2f(w2[t * 2]);
        R1[t] = tv * bf2f(w2[t * 2 + 1]);
    }
    __syncthreads();
    for (int o = 64; o; o >>= 1) {
        if (t < o) { R0[t] += R0[t + o]; R1[t] += R1[t + o]; }
        __syncthreads();
    }
    if (t == 0) {
        float z0 = R0[0] + bf2f(b2[0]);
        float z1 = R1[0] + bf2f(b2[1]);
        float m = fmaxf(z0, z1);
        float l = m + logf(expf(z0 - m) + expf(z1 - m));
        float o0 = z0 - l, o1 = z1 - l;
        if (*flag) {
            ((float*)out)[2 * g]     = o0;
            ((float*)out)[2 * g + 1] = o1;
        } else {
            ((ushort*)out)[2 * g]     = f2bf(o0);
            ((ushort*)out)[2 * g + 1] = f2bf(o1);
        }
    }
}

extern "C" void kernel_launch(void* const* d_in, const int* in_sizes, int n_in,
                              void* d_out, int out_size, void* d_ws, size_t ws_size,
                              hipStream_t stream) {
    const void* x      = d_in[0];
    const int*  ei     = (const int*)d_in[1];
    const int*  batch  = (const int*)d_in[2];

    const int N = in_sizes[0] / 128;   // 50000 nodes
    const int E = in_sizes[1] / 2;     // 600000 edges
    const int G = out_size / 2;        // 64 graphs
    const int* srcIdx = ei;
    const int* dstIdx = ei + E;

    char* ws = (char*)d_ws;
    size_t off = 0;
    auto alloc = [&](size_t bytes) -> void* {
        off = (off + 255) & ~(size_t)255;
        void* p = ws + off;
        off += bytes;
        return p;
    };
    int*    flag    = (int*)alloc(4);
    int*    deg     = (int*)alloc((size_t)N * 4);
    int*    rowptr  = (int*)alloc((size_t)(N + 1) * 4);
    int*    cursor  = (int*)alloc((size_t)N * 4);
    int*    csr_src = (int*)alloc((size_t)E * 4);
    int*    csums   = (int*)alloc(((size_t)N / SCAN_CHUNK + 2) * 4);
    ushort* Wt0     = (ushort*)alloc(128 * 128 * 2);
    ushort* WtA0    = (ushort*)alloc(256 * 128 * 2);
    ushort* Wt1     = (ushort*)alloc(128 * 128 * 2);
    ushort* WtA1    = (ushort*)alloc(256 * 128 * 2);
    ushort* small   = (ushort*)alloc(17282 * 2);
    ushort* xb      = (ushort*)alloc((size_t)N * 128 * 2);
    ushort* msg     = (ushort*)alloc((size_t)N * 128 * 2);
    ushort* agg     = (ushort*)alloc((size_t)N * 128 * 2);
    ushort* h0      = (ushort*)alloc((size_t)N * 128 * 2);
    int*    pooled  = (int*)alloc((size_t)G * 128 * 4);

    // dtype sniff
    sniff_kernel<<<1, 256, 0, stream>>>((const uint*)x, flag);

    // phase A: convert x + weight prep + zero deg/pooled
    SmallSrcs ss;
    ss.p[0] = d_in[4];  ss.p[1] = d_in[6];  ss.p[2] = d_in[8];  ss.p[3] = d_in[10];
    ss.p[4] = d_in[11]; ss.p[5] = d_in[12]; ss.p[6] = d_in[13]; ss.p[7] = d_in[14];
    int nbconv = (N * 128 + 2047) / 2048;
    int nbzero = ((N / 4 + 1 + G * 32) + 255) / 256;
    phaseA<<<nbconv + 452 + nbzero, 256, 0, stream>>>(
        x, xb, N * 128, nbconv,
        d_in[3], d_in[5], d_in[7], d_in[9],
        Wt0, WtA0, Wt1, WtA1, ss, small, deg, pooled, N, G, flag);

    int gb = (N + 127) / 128;
    int ab = (N + 3) / 4;
    int eb = (E + 255) / 256;

    // layer-0 lin GEMM (independent of CSR)
    gemm_kernel<1, false, false, false><<<gb, 256, 0, stream>>>(
        xb, xb, Wt0, small + 0, msg, N, nullptr, nullptr, nullptr, nullptr, nullptr);

    // CSR build
    count_deg<<<eb, 256, 0, stream>>>(dstIdx, deg, E);
    int nchunks = (N + SCAN_CHUNK - 1) / SCAN_CHUNK;
    chunk_sum_kernel<<<nchunks, 256, 0, stream>>>(deg, csums, N);
    scan_phase2<<<N / SCAN_CHUNK + 1, 256, 0, stream>>>(deg, csums, rowptr, cursor, N);
    fill_kernel<<<eb, 256, 0, stream>>>(srcIdx, dstIdx, cursor, csr_src, E);

    // layer 0 aggregate + fused (upd0 -> h0) + (lin1 -> msg)
    aggregate_kernel<<<ab, 256, 0, stream>>>(msg, rowptr, csr_src, agg, N);
    gemm_kernel<2, true, false, true><<<gb, 256, 0, stream>>>(
        agg, xb, WtA0, small + 128, h0, N, nullptr, nullptr, Wt1, small + 256, msg);

    // layer 1 aggregate + fused upd1+max-pool
    aggregate_kernel<<<ab, 256, 0, stream>>>(msg, rowptr, csr_src, agg, N);
    gemm_kernel<2, true, true, false><<<gb, 256, 0, stream>>>(
        agg, h0, WtA1, small + 384, nullptr, N, batch, pooled, nullptr, nullptr, nullptr);

    // head
    final_kernel<<<G, 256, 0, stream>>>((const float*)pooled, small, d_out, G, flag);
}